// Round 1
// baseline (942.064 us; speedup 1.0000x reference)
//
#include <hip/hip_runtime.h>
#include <cstdint>
#include <cstddef>

#define S_TOT 2048
#define S0_   1023
#define S1_   1025
#define D_    256
#define D2_   512
#define DZ_   128
#define NB_   8
#define SCALE_INV (1.0f/16.0f)

__device__ __forceinline__ float warp_sum(float v){
  #pragma unroll
  for(int o=32;o;o>>=1) v += __shfl_down(v,o,64);
  return v;
}
__device__ __forceinline__ float warp_max(float v){
  #pragma unroll
  for(int o=32;o;o>>=1) v = fmaxf(v, __shfl_down(v,o,64));
  return v;
}
__device__ __forceinline__ float block_sum(float v, float* red){
  int tid = threadIdx.x;
  v = warp_sum(v);
  __syncthreads();
  if((tid&63)==0) red[tid>>6] = v;
  __syncthreads();
  return red[0]+red[1]+red[2]+red[3];
}
__device__ __forceinline__ float block_max(float v, float* red){
  int tid = threadIdx.x;
  v = warp_max(v);
  __syncthreads();
  if((tid&63)==0) red[tid>>6] = v;
  __syncthreads();
  return fmaxf(fmaxf(red[0],red[1]),fmaxf(red[2],red[3]));
}
__device__ __forceinline__ float silu_f(float x){ return x / (1.f + __expf(-x)); }

// ---------------- kernel 1: x = LN(seq@W_init+b); U/V/Z projections ----------
__global__ __launch_bounds__(256) void k_proj(
    const float* __restrict__ seq,
    const float* __restrict__ W_init, const float* __restrict__ b_init,
    const float* __restrict__ ln_g, const float* __restrict__ ln_b,
    const float* __restrict__ W_U, const float* __restrict__ b_U,
    const float* __restrict__ W_V, const float* __restrict__ b_V,
    const float* __restrict__ W_Z, const float* __restrict__ b_Z,
    float* __restrict__ Zb, float* __restrict__ Ub, float* __restrict__ Vb)
{
  const int tid = threadIdx.x;
  const int g0 = blockIdx.x * 4;
  __shared__ float s_in[4][D_];
  __shared__ float s_x[4][D_];
  __shared__ float red[4];

  #pragma unroll
  for(int r=0;r<4;++r) s_in[r][tid] = seq[(size_t)(g0+r)*D_ + tid];
  __syncthreads();

  float t0=0.f,t1=0.f,t2=0.f,t3=0.f;
  for(int k=0;k<D_;++k){
    float w = W_init[k*D_ + tid];
    t0 += s_in[0][k]*w; t1 += s_in[1][k]*w; t2 += s_in[2][k]*w; t3 += s_in[3][k]*w;
  }
  float bi = b_init[tid];
  float tv[4] = {t0+bi, t1+bi, t2+bi, t3+bi};
  float lg = ln_g[tid], lb = ln_b[tid];
  #pragma unroll
  for(int r=0;r<4;++r){
    float m = block_sum(tv[r], red) * (1.f/D_);
    float dd = tv[r]-m;
    float v = block_sum(dd*dd, red) * (1.f/D_);
    s_x[r][tid] = dd * rsqrtf(v + 1e-5f) * lg + lb;
  }
  __syncthreads();

  for(int r=0;r<4;++r){
    int g = g0 + r;
    int b = g >> 11;        // /2048
    int s = g & 2047;
    if (s < S0_) {
      float a0=0.f, a1=0.f;
      for(int k=0;k<D_;++k){
        float xv = s_x[r][k];
        a0 += xv * W_U[k*D2_ + tid];
        a1 += xv * W_U[k*D2_ + tid + 256];
      }
      a0 += b_U[tid]; a1 += b_U[tid+256];
      size_t ro = ((size_t)b*S0_ + s)*D2_;
      Ub[ro+tid]     = silu_f(a0);
      Ub[ro+tid+256] = silu_f(a1);
    } else {
      float a0=0.f, a1=0.f;
      for(int k=0;k<D_;++k){
        float xv = s_x[r][k];
        a0 += xv * W_V[k*D2_ + tid];
        a1 += xv * W_V[k*D2_ + tid + 256];
      }
      a0 += b_V[tid]; a1 += b_V[tid+256];
      size_t ro = ((size_t)b*S1_ + (s - S0_))*D2_;
      Vb[ro+tid]     = silu_f(a0);
      Vb[ro+tid+256] = silu_f(a1);
    }
    if (tid < DZ_) {
      float a=0.f;
      for(int k=0;k<D_;++k) a += s_x[r][k]*W_Z[k*DZ_ + tid];
      a += b_Z[tid];
      Zb[(size_t)g*DZ_ + tid] = silu_f(a);
    }
  }
}

// ---------------- kernel 2: attention -----------------------------------
#define RQ 8
__global__ __launch_bounds__(256) void k_attn(
    const float* __restrict__ Zb, const float* __restrict__ Vb,
    float* __restrict__ Ub,                     // in: U, out: U * V_
    const unsigned char* __restrict__ amask,    // (N,S,S) bool
    const int* __restrict__ heights,            // (N,S) int32
    const float* __restrict__ os_gamma, const float* __restrict__ os_beta,
    const float* __restrict__ embedH)           // (10,128)
{
  const int tid = threadIdx.x;
  const int grp = blockIdx.x;       // 0..127
  const int b   = blockIdx.y;       // 0..7
  const int sbase = grp * RQ;
  const int Rv = min(RQ, S0_ - sbase);

  __shared__ float s_qg[RQ][DZ_];
  __shared__ float s_qh[RQ][10];
  __shared__ float s_qb[RQ];
  __shared__ float s_tmp[DZ_];
  __shared__ float s_qp[DZ_];
  __shared__ int   s_hrow[S1_];
  __shared__ int   s_hs[RQ];
  __shared__ float s_p[RQ][S1_];
  __shared__ float red[4];

  for(int t=tid;t<S1_;t+=256) s_hrow[t] = heights[b*S_TOT + S0_ + t];
  if (tid < RQ) {
    int s = sbase + tid;
    s_hs[tid] = heights[b*S_TOT + (s < S0_ ? s : S0_-1)];
  }

  const float* G0 = os_gamma;         const float* B0 = os_beta;
  const float* G1 = os_gamma + DZ_;   const float* B1 = os_beta + DZ_;
  const float* G2 = os_gamma + 2*DZ_; const float* B2 = os_beta + 2*DZ_;

  for(int r=0;r<Rv;++r){
    int s = sbase + r;
    const float* z = Zb + (size_t)(b*S_TOT + s)*DZ_;
    __syncthreads();
    if (tid < DZ_) {
      float zv = z[tid];
      float q  = zv*G0[tid] + B0[tid];
      float qp = zv*G1[tid] + B1[tid];
      s_qg[r][tid] = q * G2[tid];
      s_tmp[tid]   = q * B2[tid];
      s_qp[tid]    = qp;
    }
    __syncthreads();
    if (tid < 10) {
      float a=0.f;
      for(int k=0;k<DZ_;++k) a += s_qp[k]*embedH[tid*DZ_+k];
      s_qh[r][tid] = a;
    } else if (tid == 16) {
      float a=0.f;
      for(int k=0;k<DZ_;++k) a += s_tmp[k];
      s_qb[r] = a;
    }
  }
  __syncthreads();

  // phase 1: logits
  for(int t=tid;t<S1_;t+=256){
    const float* zk = Zb + (size_t)(b*S_TOT + S0_ + t)*DZ_;
    float e[RQ];
    #pragma unroll
    for(int r=0;r<RQ;++r) e[r] = 0.f;
    for(int k=0;k<DZ_;k+=4){
      float4 z4 = *reinterpret_cast<const float4*>(zk + k);
      #pragma unroll
      for(int r=0;r<RQ;++r){
        e[r] += s_qg[r][k]*z4.x + s_qg[r][k+1]*z4.y + s_qg[r][k+2]*z4.z + s_qg[r][k+3]*z4.w;
      }
    }
    int ht = s_hrow[t];
    #pragma unroll
    for(int r=0;r<RQ;++r){
      int idx = min(max(ht - s_hs[r], 1), 10) - 1;
      float l = (e[r] + s_qb[r] + s_qh[r][idx]) * SCALE_INV;
      unsigned char mk = amask[((size_t)(b*S_TOT) + (size_t)(sbase+r))*S_TOT + S0_ + t];
      s_p[r][t] = mk ? l : -9999.f;
    }
  }
  __syncthreads();

  // softmax per row
  for(int r=0;r<Rv;++r){
    float m = -1e30f;
    for(int t=tid;t<S1_;t+=256) m = fmaxf(m, s_p[r][t]);
    m = block_max(m, red);
    float sum = 0.f;
    for(int t=tid;t<S1_;t+=256){ float p = __expf(s_p[r][t]-m); s_p[r][t]=p; sum+=p; }
    sum = block_sum(sum, red);
    float inv = 1.f/sum;
    for(int t=tid;t<S1_;t+=256) s_p[r][t] *= inv;
  }
  __syncthreads();

  // phase 2: V_ = attn @ V ; write U*V_ in place into Ub
  float acc0[RQ], acc1[RQ];
  #pragma unroll
  for(int r=0;r<RQ;++r){acc0[r]=0.f;acc1[r]=0.f;}
  const float* vb = Vb + (size_t)b*S1_*D2_;
  for(int t=0;t<S1_;++t){
    float v0 = vb[(size_t)t*D2_ + tid];
    float v1 = vb[(size_t)t*D2_ + tid + 256];
    #pragma unroll
    for(int r=0;r<RQ;++r){
      float p = s_p[r][t];
      acc0[r] += p*v0; acc1[r] += p*v1;
    }
  }
  for(int r=0;r<Rv;++r){
    size_t ro = ((size_t)b*S0_ + sbase + r)*D2_;
    float u0 = Ub[ro+tid], u1 = Ub[ro+tid+256];
    Ub[ro+tid]     = u0*acc0[r];
    Ub[ro+tid+256] = u1*acc1[r];
  }
}

// ---------------- kernel 3: out proj + gating -----------------------------
__global__ __launch_bounds__(256) void k_out(
    const float* __restrict__ UVb, const float* __restrict__ seq,
    const float* __restrict__ W_out, const float* __restrict__ b_out,
    const float* __restrict__ W_gate, const float* __restrict__ b_gate,
    float* __restrict__ out)
{
  const int tid = threadIdx.x;
  const int g0 = blockIdx.x * 4;   // row in [0, 8184)
  __shared__ float s_uv[4][D2_];
  __shared__ float s_o[4][D_];
  __shared__ float s_res[4][D_];

  #pragma unroll
  for(int r=0;r<4;++r){
    int g = g0 + r;
    int b = g / S0_;
    int s = g - b*S0_;
    size_t ro = (size_t)g * D2_;
    s_uv[r][tid]     = UVb[ro + tid];
    s_uv[r][tid+256] = UVb[ro + tid + 256];
    s_res[r][tid]    = seq[((size_t)b*S_TOT + s)*D_ + tid];
  }
  __syncthreads();

  float ov[4];
  float bo = b_out[tid];
  #pragma unroll
  for(int r=0;r<4;++r){
    float a=0.f;
    for(int k=0;k<D2_;++k) a += s_uv[r][k]*W_out[k*D_ + tid];
    ov[r] = a + bo;
    s_o[r][tid] = ov[r];
  }
  __syncthreads();

  float bg = b_gate[tid];
  #pragma unroll
  for(int r=0;r<4;++r){
    float a=0.f;
    for(int k=0;k<D_;++k) a += s_o[r][k]*W_gate[k*D_ + tid];
    for(int k=0;k<D_;++k) a += s_res[r][k]*W_gate[(k+D_)*D_ + tid];
    float gte = 1.f/(1.f+__expf(-(a+bg)));
    int g = g0 + r;
    int b = g / S0_;
    int s = g - b*S0_;
    out[((size_t)b*S_TOT + s)*D_ + tid] = gte*ov[r] + (1.f-gte)*s_res[r][tid];
  }
}

// ---------------- kernel 4: passthrough tail rows -------------------------
__global__ void k_copy(const float* __restrict__ seq, float* __restrict__ out){
  const int per_b = S1_ * (D_/4);           // 65600 float4 per batch
  const int total = NB_ * per_b;            // 524800
  for (int i = blockIdx.x*blockDim.x + threadIdx.x; i < total; i += gridDim.x*blockDim.x) {
    int b = i / per_b;
    int off = i - b*per_b;
    size_t base = ((size_t)b*S_TOT + S0_) * (size_t)(D_/4);
    reinterpret_cast<float4*>(out)[base + off] =
        reinterpret_cast<const float4*>(seq)[base + off];
  }
}

extern "C" void kernel_launch(void* const* d_in, const int* in_sizes, int n_in,
                              void* d_out, int out_size, void* d_ws, size_t ws_size,
                              hipStream_t stream)
{
  const float* seq    = (const float*)d_in[0];
  const unsigned char* amask = (const unsigned char*)d_in[1];
  const int*   heights= (const int*)d_in[2];
  const float* W_init = (const float*)d_in[3];
  const float* b_init = (const float*)d_in[4];
  const float* ln_g   = (const float*)d_in[5];
  const float* ln_b   = (const float*)d_in[6];
  const float* W_U    = (const float*)d_in[7];
  const float* b_U    = (const float*)d_in[8];
  const float* W_V    = (const float*)d_in[9];
  const float* b_V    = (const float*)d_in[10];
  const float* W_Z    = (const float*)d_in[11];
  const float* b_Z    = (const float*)d_in[12];
  const float* os_g   = (const float*)d_in[13];
  const float* os_b   = (const float*)d_in[14];
  const float* embH   = (const float*)d_in[15];
  const float* W_out  = (const float*)d_in[16];
  const float* b_out  = (const float*)d_in[17];
  const float* W_gate = (const float*)d_in[18];
  const float* b_gate = (const float*)d_in[19];
  float* out = (float*)d_out;

  float* Zb = (float*)d_ws;                          // 16384*128 floats
  float* Ub = Zb + (size_t)16384*128;                // 8184*512 floats (U, then U*V_)
  float* Vb = Ub + (size_t)8184*512;                 // 8200*512 floats

  hipLaunchKernelGGL(k_proj, dim3(4096), dim3(256), 0, stream,
      seq, W_init, b_init, ln_g, ln_b, W_U, b_U, W_V, b_V, W_Z, b_Z, Zb, Ub, Vb);
  hipLaunchKernelGGL(k_attn, dim3(128, 8), dim3(256), 0, stream,
      Zb, Vb, Ub, amask, heights, os_g, os_b, embH);
  hipLaunchKernelGGL(k_out, dim3(2046), dim3(256), 0, stream,
      Ub, seq, W_out, b_out, W_gate, b_gate, out);
  hipLaunchKernelGGL(k_copy, dim3(512), dim3(256), 0, stream, seq, out);
}

// Round 2
// 487.140 us; speedup vs baseline: 1.9339x; 1.9339x over previous
//
#include <hip/hip_runtime.h>
#include <cstdint>
#include <cstddef>

#define S_TOT 2048
#define S0_   1023
#define S1_   1025
#define D_    256
#define D2_   512
#define DZ_   128
#define NB_   8
#define SCALE_INV (1.0f/16.0f)
#define XPAD  264   // 256 + 8 bf16 pad (row stride 528B -> 2-way LDS conflicts only)

typedef __attribute__((ext_vector_type(8))) short short8v;
typedef __attribute__((ext_vector_type(4))) short short4v;
typedef __attribute__((ext_vector_type(4))) float f32x4;

__device__ __forceinline__ short f2bf(float f){
  unsigned u = __float_as_uint(f);
  unsigned r = (u + 0x7FFFu + ((u >> 16) & 1u)) >> 16;
  return (short)r;
}
__device__ __forceinline__ float silu_f(float x){ return x / (1.f + __expf(-x)); }

__device__ __forceinline__ float warp_sum(float v){
  #pragma unroll
  for(int o=32;o;o>>=1) v += __shfl_down(v,o,64);
  return v;
}
__device__ __forceinline__ float warp_max(float v){
  #pragma unroll
  for(int o=32;o;o>>=1) v = fmaxf(v, __shfl_down(v,o,64));
  return v;
}
__device__ __forceinline__ float block_sum(float v, float* red){
  int tid = threadIdx.x;
  v = warp_sum(v);
  __syncthreads();
  if((tid&63)==0) red[tid>>6] = v;
  __syncthreads();
  return red[0]+red[1]+red[2]+red[3];
}
__device__ __forceinline__ float block_max(float v, float* red){
  int tid = threadIdx.x;
  v = warp_max(v);
  __syncthreads();
  if((tid&63)==0) red[tid>>6] = v;
  __syncthreads();
  return fmaxf(fmaxf(red[0],red[1]),fmaxf(red[2],red[3]));
}

// Load an A fragment (mfma_f32_16x16x32_bf16) from a row-major LDS row.
// elems 0..3: k = kt*32 + (lane>>4)*4 + j ; elems 4..7: +16
__device__ __forceinline__ short8v load_afrag(const short* arow, int kt, int khi){
  short4v lo = *reinterpret_cast<const short4v*>(arow + kt*32 + khi);
  short4v hi = *reinterpret_cast<const short4v*>(arow + kt*32 + khi + 16);
  short8v r = {lo[0],lo[1],lo[2],lo[3],hi[0],hi[1],hi[2],hi[3]};
  return r;
}

// ---------------- weight pack: fp32 (K,N) -> bf16 MFMA-B-fragment order -----
// tile index = nt*KT + kt ; per tile: 64 lanes x 8 elems (16B per lane)
// elem j of lane l = W[kt*32 + (l>>4)*4 + (j&3) + 16*(j>>2)][nt*16 + (l&15)]
__global__ __launch_bounds__(256) void k_pack(const float* __restrict__ W,
                                              short* __restrict__ dst,
                                              int K, int N){
  const int wv = threadIdx.x >> 6, lane = threadIdx.x & 63;
  const int KT = K >> 5, NT = N >> 4;
  const int tile = blockIdx.x*4 + wv;
  if (tile >= KT*NT) return;
  const int nt = tile / KT, kt = tile - nt*KT;
  const int n = nt*16 + (lane & 15);
  const int kbase = kt*32 + ((lane>>4)<<2);
  short8v v;
  #pragma unroll
  for (int j=0;j<8;++j){
    int k = kbase + (j&3) + ((j>>2)<<4);
    v[j] = f2bf(W[(size_t)k*N + n]);
  }
  *reinterpret_cast<short8v*>(dst + ((size_t)tile*64 + lane)*8) = v;
}

// ---------------- kernel 1a: x = LN(seq@W_init + b) -> bf16 -----------------
// 64 rows/block, 4 waves x 16 rows x 16 n-tiles, K=256 (KT=8)
__global__ __launch_bounds__(256) void k_x(
    const float* __restrict__ seq, const short* __restrict__ Wp,
    const float* __restrict__ b_init,
    const float* __restrict__ ln_g, const float* __restrict__ ln_b,
    short* __restrict__ xb)
{
  __shared__ short s_a[64*XPAD];
  const int tid = threadIdx.x, lane = tid & 63, wv = tid >> 6;
  const int R0 = blockIdx.x * 64;
  const int colb = lane & 15, khi = (lane>>4)<<2;

  // stage seq rows -> bf16 LDS
  for (int c = tid; c < 64*64; c += 256){
    int row = c >> 6, c4 = (c & 63) << 2;
    float4 f = *reinterpret_cast<const float4*>(seq + (size_t)(R0+row)*D_ + c4);
    short4v h = { f2bf(f.x), f2bf(f.y), f2bf(f.z), f2bf(f.w) };
    *reinterpret_cast<short4v*>(&s_a[row*XPAD + c4]) = h;
  }
  __syncthreads();

  f32x4 acc[16];
  #pragma unroll
  for (int nt=0;nt<16;++nt) acc[nt] = (f32x4){0.f,0.f,0.f,0.f};

  const short* arow = &s_a[(wv*16 + colb)*XPAD];
  #pragma unroll
  for (int kt=0; kt<8; ++kt){
    short8v a = load_afrag(arow, kt, khi);
    #pragma unroll
    for (int nt=0; nt<16; ++nt){
      short8v b = *reinterpret_cast<const short8v*>(Wp + ((size_t)(nt*8 + kt)*64 + lane)*8);
      acc[nt] = __builtin_amdgcn_mfma_f32_16x16x32_bf16(a, b, acc[nt], 0, 0, 0);
    }
  }

  // bias + LN (rows are (lane>>4)*4+reg within wave tile; cols (lane&15)+16*nt)
  float sum[4] = {0.f,0.f,0.f,0.f};
  #pragma unroll
  for (int nt=0; nt<16; ++nt){
    float bv = b_init[nt*16 + colb];
    #pragma unroll
    for (int r=0;r<4;++r){ acc[nt][r] += bv; sum[r] += acc[nt][r]; }
  }
  #pragma unroll
  for (int r=0;r<4;++r){
    #pragma unroll
    for (int m=1;m<16;m<<=1) sum[r] += __shfl_xor(sum[r], m, 64);
    sum[r] *= (1.f/256.f);
  }
  float var[4] = {0.f,0.f,0.f,0.f};
  #pragma unroll
  for (int nt=0; nt<16; ++nt)
    #pragma unroll
    for (int r=0;r<4;++r){ float d = acc[nt][r]-sum[r]; var[r] += d*d; }
  #pragma unroll
  for (int r=0;r<4;++r){
    #pragma unroll
    for (int m=1;m<16;m<<=1) var[r] += __shfl_xor(var[r], m, 64);
    var[r] = rsqrtf(var[r]*(1.f/256.f) + 1e-5f);
  }
  // write normalized bf16 back into own wave's rows of s_a (wave-private range)
  #pragma unroll
  for (int nt=0; nt<16; ++nt){
    int col = nt*16 + colb;
    float g = ln_g[col], bb = ln_b[col];
    #pragma unroll
    for (int r=0;r<4;++r){
      float xn = (acc[nt][r]-sum[r])*var[r]*g + bb;
      s_a[(wv*16 + ((lane>>4)<<2) + r)*XPAD + col] = f2bf(xn);
    }
  }
  __syncthreads();
  // coalesced LDS -> global bf16
  for (int c = tid; c < 64*32; c += 256){
    int row = c >> 5, c8 = (c & 31) << 3;
    *reinterpret_cast<short8v*>(xb + (size_t)(R0+row)*D_ + c8) =
        *reinterpret_cast<const short8v*>(&s_a[row*XPAD + c8]);
  }
}

// ---------------- kernel 1b: generic silu(x@W+b), K=256 --------------------
// out rows map to x rows via orow -> b=orow/RPB, s=orow%RPB, xrow=b*2048+s+OFF
__global__ __launch_bounds__(256) void k_gemm(
    const short* __restrict__ xb, const short* __restrict__ Wp,
    const float* __restrict__ bias, float* __restrict__ outp,
    int M, int RPB, int OFF, int Nld)
{
  __shared__ short s_a[64*XPAD];
  const int tid = threadIdx.x, lane = tid & 63, wv = tid >> 6;
  const int wy = wv >> 1, wx = wv & 1;
  const int R0 = blockIdx.x * 64;
  const int C0 = blockIdx.y * 64;
  const int colb = lane & 15, khi = (lane>>4)<<2;

  for (int c = tid; c < 64*32; c += 256){
    int r = c >> 5, c8 = (c & 31) << 3;
    int orow = R0 + r; if (orow > M-1) orow = M-1;
    int bb = orow / RPB; int s = orow - bb*RPB;
    size_t xrow = (size_t)bb*S_TOT + s + OFF;
    *reinterpret_cast<short8v*>(&s_a[r*XPAD + c8]) =
        *reinterpret_cast<const short8v*>(xb + xrow*D_ + c8);
  }
  __syncthreads();

  f32x4 acc[2][2];
  #pragma unroll
  for(int i=0;i<2;++i)
    #pragma unroll
    for(int j=0;j<2;++j) acc[i][j] = (f32x4){0.f,0.f,0.f,0.f};

  const short* ar0 = &s_a[(wy*32 + colb)*XPAD];
  const short* ar1 = ar0 + 16*XPAD;
  const int ntg = (C0 >> 4) + wx*2;
  #pragma unroll
  for (int kt=0; kt<8; ++kt){
    short8v a0 = load_afrag(ar0, kt, khi);
    short8v a1 = load_afrag(ar1, kt, khi);
    short8v b0 = *reinterpret_cast<const short8v*>(Wp + ((size_t)((ntg+0)*8 + kt)*64 + lane)*8);
    short8v b1 = *reinterpret_cast<const short8v*>(Wp + ((size_t)((ntg+1)*8 + kt)*64 + lane)*8);
    acc[0][0] = __builtin_amdgcn_mfma_f32_16x16x32_bf16(a0, b0, acc[0][0], 0,0,0);
    acc[0][1] = __builtin_amdgcn_mfma_f32_16x16x32_bf16(a0, b1, acc[0][1], 0,0,0);
    acc[1][0] = __builtin_amdgcn_mfma_f32_16x16x32_bf16(a1, b0, acc[1][0], 0,0,0);
    acc[1][1] = __builtin_amdgcn_mfma_f32_16x16x32_bf16(a1, b1, acc[1][1], 0,0,0);
  }
  #pragma unroll
  for (int sj=0; sj<2; ++sj){
    int col = C0 + wx*32 + sj*16 + colb;
    float bv = bias[col];
    #pragma unroll
    for (int si=0; si<2; ++si){
      #pragma unroll
      for (int r=0;r<4;++r){
        int orow = R0 + wy*32 + si*16 + ((lane>>4)<<2) + r;
        if (orow < M) outp[(size_t)orow*Nld + col] = silu_f(acc[si][sj][r] + bv);
      }
    }
  }
}

// ---------------- kernel 2: attention (unchanged fp32) ----------------------
#define RQ 8
__global__ __launch_bounds__(256) void k_attn(
    const float* __restrict__ Zb, const float* __restrict__ Vb,
    float* __restrict__ Ub,
    const unsigned char* __restrict__ amask,
    const int* __restrict__ heights,
    const float* __restrict__ os_gamma, const float* __restrict__ os_beta,
    const float* __restrict__ embedH)
{
  const int tid = threadIdx.x;
  const int grp = blockIdx.x;
  const int b   = blockIdx.y;
  const int sbase = grp * RQ;
  const int Rv = min(RQ, S0_ - sbase);

  __shared__ float s_qg[RQ][DZ_];
  __shared__ float s_qh[RQ][10];
  __shared__ float s_qb[RQ];
  __shared__ float s_tmp[DZ_];
  __shared__ float s_qp[DZ_];
  __shared__ int   s_hrow[S1_];
  __shared__ int   s_hs[RQ];
  __shared__ float s_p[RQ][S1_];
  __shared__ float red[4];

  for(int t=tid;t<S1_;t+=256) s_hrow[t] = heights[b*S_TOT + S0_ + t];
  if (tid < RQ) {
    int s = sbase + tid;
    s_hs[tid] = heights[b*S_TOT + (s < S0_ ? s : S0_-1)];
  }

  const float* G0 = os_gamma;         const float* B0 = os_beta;
  const float* G1 = os_gamma + DZ_;   const float* B1 = os_beta + DZ_;
  const float* G2 = os_gamma + 2*DZ_; const float* B2 = os_beta + 2*DZ_;

  for(int r=0;r<Rv;++r){
    int s = sbase + r;
    const float* z = Zb + (size_t)(b*S_TOT + s)*DZ_;
    __syncthreads();
    if (tid < DZ_) {
      float zv = z[tid];
      float q  = zv*G0[tid] + B0[tid];
      float qp = zv*G1[tid] + B1[tid];
      s_qg[r][tid] = q * G2[tid];
      s_tmp[tid]   = q * B2[tid];
      s_qp[tid]    = qp;
    }
    __syncthreads();
    if (tid < 10) {
      float a=0.f;
      for(int k=0;k<DZ_;++k) a += s_qp[k]*embedH[tid*DZ_+k];
      s_qh[r][tid] = a;
    } else if (tid == 16) {
      float a=0.f;
      for(int k=0;k<DZ_;++k) a += s_tmp[k];
      s_qb[r] = a;
    }
  }
  __syncthreads();

  for(int t=tid;t<S1_;t+=256){
    const float* zk = Zb + (size_t)(b*S_TOT + S0_ + t)*DZ_;
    float e[RQ];
    #pragma unroll
    for(int r=0;r<RQ;++r) e[r] = 0.f;
    for(int k=0;k<DZ_;k+=4){
      float4 z4 = *reinterpret_cast<const float4*>(zk + k);
      #pragma unroll
      for(int r=0;r<RQ;++r){
        e[r] += s_qg[r][k]*z4.x + s_qg[r][k+1]*z4.y + s_qg[r][k+2]*z4.z + s_qg[r][k+3]*z4.w;
      }
    }
    int ht = s_hrow[t];
    #pragma unroll
    for(int r=0;r<RQ;++r){
      int idx = min(max(ht - s_hs[r], 1), 10) - 1;
      float l = (e[r] + s_qb[r] + s_qh[r][idx]) * SCALE_INV;
      unsigned char mk = amask[((size_t)(b*S_TOT) + (size_t)(sbase+r))*S_TOT + S0_ + t];
      s_p[r][t] = mk ? l : -9999.f;
    }
  }
  __syncthreads();

  for(int r=0;r<Rv;++r){
    float m = -1e30f;
    for(int t=tid;t<S1_;t+=256) m = fmaxf(m, s_p[r][t]);
    m = block_max(m, red);
    float sum = 0.f;
    for(int t=tid;t<S1_;t+=256){ float p = __expf(s_p[r][t]-m); s_p[r][t]=p; sum+=p; }
    sum = block_sum(sum, red);
    float inv = 1.f/sum;
    for(int t=tid;t<S1_;t+=256) s_p[r][t] *= inv;
  }
  __syncthreads();

  float acc0[RQ], acc1[RQ];
  #pragma unroll
  for(int r=0;r<RQ;++r){acc0[r]=0.f;acc1[r]=0.f;}
  const float* vb = Vb + (size_t)b*S1_*D2_;
  for(int t=0;t<S1_;++t){
    float v0 = vb[(size_t)t*D2_ + tid];
    float v1 = vb[(size_t)t*D2_ + tid + 256];
    #pragma unroll
    for(int r=0;r<RQ;++r){
      float p = s_p[r][t];
      acc0[r] += p*v0; acc1[r] += p*v1;
    }
  }
  for(int r=0;r<Rv;++r){
    size_t ro = ((size_t)b*S0_ + sbase + r)*D2_;
    float u0 = Ub[ro+tid], u1 = Ub[ro+tid+256];
    Ub[ro+tid]     = u0*acc0[r];
    Ub[ro+tid+256] = u1*acc1[r];
  }
}

// ---------------- kernel 3: fused out-proj + gating (MFMA) ------------------
// 64 rows/block, 4 waves x 16 rows x 16 n-tiles (N=256). K=512 in two halves.
__global__ __launch_bounds__(256) void k_outg(
    const float* __restrict__ UV, const float* __restrict__ seq,
    const short* __restrict__ Wpo, const float* __restrict__ b_out,
    const short* __restrict__ Wpg, const float* __restrict__ b_gate,
    float* __restrict__ out)
{
  __shared__ short bufA[64*XPAD];
  __shared__ short bufB[64*XPAD];
  const int tid = threadIdx.x, lane = tid & 63, wv = tid >> 6;
  const int R0 = blockIdx.x * 64;
  const int colb = lane & 15, khi = (lane>>4)<<2;

  f32x4 acc_o[16];
  #pragma unroll
  for (int nt=0;nt<16;++nt) acc_o[nt] = (f32x4){0.f,0.f,0.f,0.f};

  const short* arow = &bufA[(wv*16 + colb)*XPAD];

  #pragma unroll
  for (int half=0; half<2; ++half){
    __syncthreads();
    for (int c = tid; c < 64*64; c += 256){
      int r = c >> 6, c4 = (c & 63) << 2;
      int orow = min(R0 + r, 8183);
      float4 f = *reinterpret_cast<const float4*>(UV + (size_t)orow*D2_ + half*256 + c4);
      short4v h = { f2bf(f.x), f2bf(f.y), f2bf(f.z), f2bf(f.w) };
      *reinterpret_cast<short4v*>(&bufA[r*XPAD + c4]) = h;
    }
    __syncthreads();
    #pragma unroll
    for (int kt=0; kt<8; ++kt){
      short8v a = load_afrag(arow, kt, khi);
      #pragma unroll
      for (int nt=0; nt<16; ++nt){
        short8v b = *reinterpret_cast<const short8v*>(Wpo + ((size_t)(nt*16 + half*8 + kt)*64 + lane)*8);
        acc_o[nt] = __builtin_amdgcn_mfma_f32_16x16x32_bf16(a, b, acc_o[nt], 0,0,0);
      }
    }
  }
  // bias -> o held in acc_o
  #pragma unroll
  for (int nt=0; nt<16; ++nt){
    float bv = b_out[nt*16 + colb];
    #pragma unroll
    for (int r=0;r<4;++r) acc_o[nt][r] += bv;
  }
  __syncthreads();
  // repack o -> bufA (bf16), stage res -> bufB (bf16)
  #pragma unroll
  for (int nt=0; nt<16; ++nt){
    int col = nt*16 + colb;
    #pragma unroll
    for (int r=0;r<4;++r)
      bufA[(wv*16 + ((lane>>4)<<2) + r)*XPAD + col] = f2bf(acc_o[nt][r]);
  }
  for (int c = tid; c < 64*64; c += 256){
    int r = c >> 6, c4 = (c & 63) << 2;
    int orow = min(R0 + r, 8183);
    int bb = orow / S0_; int s = orow - bb*S0_;
    float4 f = *reinterpret_cast<const float4*>(seq + ((size_t)bb*S_TOT + s)*D_ + c4);
    short4v h = { f2bf(f.x), f2bf(f.y), f2bf(f.z), f2bf(f.w) };
    *reinterpret_cast<short4v*>(&bufB[r*XPAD + c4]) = h;
  }
  __syncthreads();

  f32x4 acc_g[16];
  #pragma unroll
  for (int nt=0;nt<16;++nt) acc_g[nt] = (f32x4){0.f,0.f,0.f,0.f};
  const short* arowB = &bufB[(wv*16 + colb)*XPAD];
  #pragma unroll
  for (int kt=0; kt<8; ++kt){
    short8v a = load_afrag(arow, kt, khi);
    #pragma unroll
    for (int nt=0; nt<16; ++nt){
      short8v b = *reinterpret_cast<const short8v*>(Wpg + ((size_t)(nt*16 + kt)*64 + lane)*8);
      acc_g[nt] = __builtin_amdgcn_mfma_f32_16x16x32_bf16(a, b, acc_g[nt], 0,0,0);
    }
  }
  #pragma unroll
  for (int kt=0; kt<8; ++kt){
    short8v a = load_afrag(arowB, kt, khi);
    #pragma unroll
    for (int nt=0; nt<16; ++nt){
      short8v b = *reinterpret_cast<const short8v*>(Wpg + ((size_t)(nt*16 + 8 + kt)*64 + lane)*8);
      acc_g[nt] = __builtin_amdgcn_mfma_f32_16x16x32_bf16(a, b, acc_g[nt], 0,0,0);
    }
  }
  // sigmoid gate + mix (res re-read fp32 from global for accuracy)
  #pragma unroll
  for (int nt=0; nt<16; ++nt){
    int col = nt*16 + colb;
    float bg = b_gate[col];
    #pragma unroll
    for (int r=0;r<4;++r){
      int orow = R0 + wv*16 + ((lane>>4)<<2) + r;
      if (orow < 8184){
        int bb = orow / S0_; int s = orow - bb*S0_;
        float res = seq[((size_t)bb*S_TOT + s)*D_ + col];
        float g = 1.f/(1.f + __expf(-(acc_g[nt][r] + bg)));
        out[((size_t)bb*S_TOT + s)*D_ + col] = g*acc_o[nt][r] + (1.f-g)*res;
      }
    }
  }
}

// ---------------- kernel 4: passthrough tail rows ---------------------------
__global__ void k_copy(const float* __restrict__ seq, float* __restrict__ out){
  const int per_b = S1_ * (D_/4);
  const int total = NB_ * per_b;
  for (int i = blockIdx.x*blockDim.x + threadIdx.x; i < total; i += gridDim.x*blockDim.x) {
    int b = i / per_b;
    int off = i - b*per_b;
    size_t base = ((size_t)b*S_TOT + S0_) * (size_t)(D_/4);
    reinterpret_cast<float4*>(out)[base + off] =
        reinterpret_cast<const float4*>(seq)[base + off];
  }
}

extern "C" void kernel_launch(void* const* d_in, const int* in_sizes, int n_in,
                              void* d_out, int out_size, void* d_ws, size_t ws_size,
                              hipStream_t stream)
{
  const float* seq    = (const float*)d_in[0];
  const unsigned char* amask = (const unsigned char*)d_in[1];
  const int*   heights= (const int*)d_in[2];
  const float* W_init = (const float*)d_in[3];
  const float* b_init = (const float*)d_in[4];
  const float* ln_g   = (const float*)d_in[5];
  const float* ln_b   = (const float*)d_in[6];
  const float* W_U    = (const float*)d_in[7];
  const float* b_U    = (const float*)d_in[8];
  const float* W_V    = (const float*)d_in[9];
  const float* b_V    = (const float*)d_in[10];
  const float* W_Z    = (const float*)d_in[11];
  const float* b_Z    = (const float*)d_in[12];
  const float* os_g   = (const float*)d_in[13];
  const float* os_b   = (const float*)d_in[14];
  const float* embH   = (const float*)d_in[15];
  const float* W_out  = (const float*)d_in[16];
  const float* b_out  = (const float*)d_in[17];
  const float* W_gate = (const float*)d_in[18];
  const float* b_gate = (const float*)d_in[19];
  float* out = (float*)d_out;

  char* w = (char*)d_ws;
  float* Zb = (float*)w;                 w += (size_t)16384*128*4;
  float* Ub = (float*)w;                 w += (size_t)8184*512*4;
  float* Vb = (float*)w;                 w += (size_t)8200*512*4;
  short* xb = (short*)w;                 w += (size_t)16384*256*2;
  short* WpI = (short*)w;                w += (size_t)65536*2;   // 256x256
  short* WpU = (short*)w;                w += (size_t)131072*2;  // 256x512
  short* WpV = (short*)w;                w += (size_t)131072*2;  // 256x512
  short* WpZ = (short*)w;                w += (size_t)32768*2;   // 256x128
  short* WpO = (short*)w;                w += (size_t)131072*2;  // 512x256
  short* WpG = (short*)w;                w += (size_t)131072*2;  // 512x256

  hipLaunchKernelGGL(k_pack, dim3(32), dim3(256), 0, stream, W_init, WpI, 256, 256);
  hipLaunchKernelGGL(k_pack, dim3(64), dim3(256), 0, stream, W_U,   WpU, 256, 512);
  hipLaunchKernelGGL(k_pack, dim3(64), dim3(256), 0, stream, W_V,   WpV, 256, 512);
  hipLaunchKernelGGL(k_pack, dim3(16), dim3(256), 0, stream, W_Z,   WpZ, 256, 128);
  hipLaunchKernelGGL(k_pack, dim3(64), dim3(256), 0, stream, W_out, WpO, 512, 256);
  hipLaunchKernelGGL(k_pack, dim3(64), dim3(256), 0, stream, W_gate,WpG, 512, 256);

  hipLaunchKernelGGL(k_x, dim3(256), dim3(256), 0, stream,
      seq, WpI, b_init, ln_g, ln_b, xb);

  // U: M=8184 rows (b*1023+s), V: M=8200 (b*1025+s, OFF=1023), Z: M=16384
  hipLaunchKernelGGL(k_gemm, dim3(128, 8), dim3(256), 0, stream,
      xb, WpU, b_U, Ub, 8184, 1023, 0, 512);
  hipLaunchKernelGGL(k_gemm, dim3(129, 8), dim3(256), 0, stream,
      xb, WpV, b_V, Vb, 8200, 1025, 1023, 512);
  hipLaunchKernelGGL(k_gemm, dim3(256, 2), dim3(256), 0, stream,
      xb, WpZ, b_Z, Zb, 16384, 2048, 0, 128);

  hipLaunchKernelGGL(k_attn, dim3(128, 8), dim3(256), 0, stream,
      Zb, Vb, Ub, amask, heights, os_g, os_b, embH);

  hipLaunchKernelGGL(k_outg, dim3(128), dim3(256), 0, stream,
      Ub, seq, WpO, b_out, WpG, b_gate, out);

  hipLaunchKernelGGL(k_copy, dim3(512), dim3(256), 0, stream, seq, out);
}

// Round 3
// 460.326 us; speedup vs baseline: 2.0465x; 1.0582x over previous
//
#include <hip/hip_runtime.h>
#include <cstdint>
#include <cstddef>

#define S_TOT 2048
#define S0_   1023
#define S1_   1025
#define D_    256
#define D2_   512
#define DZ_   128
#define NB_   8
#define KPAD  1088           // 17 * 64 padded keys
#define NT_   17
#define SCALE_INV (1.0f/16.0f)
#define XPAD  264            // 256 + 8 bf16 pad

typedef __attribute__((ext_vector_type(8))) short short8v;
typedef __attribute__((ext_vector_type(4))) short short4v;
typedef __attribute__((ext_vector_type(4))) float f32x4;
typedef unsigned long long u64;

__device__ __forceinline__ short f2bf(float f){
  unsigned u = __float_as_uint(f);
  unsigned r = (u + 0x7FFFu + ((u >> 16) & 1u)) >> 16;
  return (short)r;
}
__device__ __forceinline__ float bf2f(short s){
  return __uint_as_float(((unsigned)(unsigned short)s) << 16);
}
__device__ __forceinline__ float silu_f(float x){ return x / (1.f + __expf(-x)); }

// A/B fragment load from a row-major row (verified layout, round 1):
// elems 0..3: k = kt*32 + khi + j ; elems 4..7: +16
__device__ __forceinline__ short8v load_afrag(const short* arow, int kt, int khi){
  short4v lo = *reinterpret_cast<const short4v*>(arow + kt*32 + khi);
  short4v hi = *reinterpret_cast<const short4v*>(arow + kt*32 + khi + 16);
  short8v r = {lo[0],lo[1],lo[2],lo[3],hi[0],hi[1],hi[2],hi[3]};
  return r;
}

// ---------------- weight pack: fp32 (K,N) -> bf16 MFMA-B-fragment order -----
__global__ __launch_bounds__(256) void k_pack(const float* __restrict__ W,
                                              short* __restrict__ dst,
                                              int K, int N){
  const int wv = threadIdx.x >> 6, lane = threadIdx.x & 63;
  const int KT = K >> 5, NT = N >> 4;
  const int tile = blockIdx.x*4 + wv;
  if (tile >= KT*NT) return;
  const int nt = tile / KT, kt = tile - nt*KT;
  const int n = nt*16 + (lane & 15);
  const int kbase = kt*32 + ((lane>>4)<<2);
  short8v v;
  #pragma unroll
  for (int j=0;j<8;++j){
    int k = kbase + (j&3) + ((j>>2)<<4);
    v[j] = f2bf(W[(size_t)k*N + n]);
  }
  *reinterpret_cast<short8v*>(dst + ((size_t)tile*64 + lane)*8) = v;
}

// ---------------- mask pack: bool bytes -> u64 bitmask per 64-key tile ------
__global__ __launch_bounds__(256) void k_maskpack(const unsigned char* __restrict__ amask,
                                                  u64* __restrict__ maskb){
  const int lane = threadIdx.x & 63;
  const int w = blockIdx.x*4 + (threadIdx.x >> 6);
  if (w >= NB_*S0_*NT_) return;
  int b = w / (S0_*NT_);
  int rem = w - b*(S0_*NT_);
  int q = rem / NT_;
  int t = rem - q*NT_;
  int key = t*64 + lane;
  unsigned char v = 0;
  if (key < S1_) v = amask[((size_t)(b*S_TOT + q))*S_TOT + S0_ + key];
  u64 bits = __ballot(v != 0);
  if (lane == 0) maskb[w] = bits;
}

// ---------------- kernel 1a: x = LN(seq@W_init + b) -> bf16 -----------------
__global__ __launch_bounds__(256) void k_x(
    const float* __restrict__ seq, const short* __restrict__ Wp,
    const float* __restrict__ b_init,
    const float* __restrict__ ln_g, const float* __restrict__ ln_b,
    short* __restrict__ xb)
{
  __shared__ short s_a[64*XPAD];
  const int tid = threadIdx.x, lane = tid & 63, wv = tid >> 6;
  const int R0 = blockIdx.x * 64;
  const int colb = lane & 15, khi = (lane>>4)<<2;

  for (int c = tid; c < 64*64; c += 256){
    int row = c >> 6, c4 = (c & 63) << 2;
    float4 f = *reinterpret_cast<const float4*>(seq + (size_t)(R0+row)*D_ + c4);
    short4v h = { f2bf(f.x), f2bf(f.y), f2bf(f.z), f2bf(f.w) };
    *reinterpret_cast<short4v*>(&s_a[row*XPAD + c4]) = h;
  }
  __syncthreads();

  f32x4 acc[16];
  #pragma unroll
  for (int nt=0;nt<16;++nt) acc[nt] = (f32x4){0.f,0.f,0.f,0.f};

  const short* arow = &s_a[(wv*16 + colb)*XPAD];
  #pragma unroll
  for (int kt=0; kt<8; ++kt){
    short8v a = load_afrag(arow, kt, khi);
    #pragma unroll
    for (int nt=0; nt<16; ++nt){
      short8v b = *reinterpret_cast<const short8v*>(Wp + ((size_t)(nt*8 + kt)*64 + lane)*8);
      acc[nt] = __builtin_amdgcn_mfma_f32_16x16x32_bf16(a, b, acc[nt], 0, 0, 0);
    }
  }

  float sum[4] = {0.f,0.f,0.f,0.f};
  #pragma unroll
  for (int nt=0; nt<16; ++nt){
    float bv = b_init[nt*16 + colb];
    #pragma unroll
    for (int r=0;r<4;++r){ acc[nt][r] += bv; sum[r] += acc[nt][r]; }
  }
  #pragma unroll
  for (int r=0;r<4;++r){
    #pragma unroll
    for (int m=1;m<16;m<<=1) sum[r] += __shfl_xor(sum[r], m, 64);
    sum[r] *= (1.f/256.f);
  }
  float var[4] = {0.f,0.f,0.f,0.f};
  #pragma unroll
  for (int nt=0; nt<16; ++nt)
    #pragma unroll
    for (int r=0;r<4;++r){ float d = acc[nt][r]-sum[r]; var[r] += d*d; }
  #pragma unroll
  for (int r=0;r<4;++r){
    #pragma unroll
    for (int m=1;m<16;m<<=1) var[r] += __shfl_xor(var[r], m, 64);
    var[r] = rsqrtf(var[r]*(1.f/256.f) + 1e-5f);
  }
  #pragma unroll
  for (int nt=0; nt<16; ++nt){
    int col = nt*16 + colb;
    float g = ln_g[col], bb = ln_b[col];
    #pragma unroll
    for (int r=0;r<4;++r){
      float xn = (acc[nt][r]-sum[r])*var[r]*g + bb;
      s_a[(wv*16 + ((lane>>4)<<2) + r)*XPAD + col] = f2bf(xn);
    }
  }
  __syncthreads();
  for (int c = tid; c < 64*32; c += 256){
    int row = c >> 5, c8 = (c & 31) << 3;
    *reinterpret_cast<short8v*>(xb + (size_t)(R0+row)*D_ + c8) =
        *reinterpret_cast<const short8v*>(&s_a[row*XPAD + c8]);
  }
}

// ---------------- kernel 1b: U = silu(x@W+b), fp32 out ---------------------
__global__ __launch_bounds__(256) void k_gemm(
    const short* __restrict__ xb, const short* __restrict__ Wp,
    const float* __restrict__ bias, float* __restrict__ outp,
    int M, int RPB, int OFF, int Nld)
{
  __shared__ short s_a[64*XPAD];
  const int tid = threadIdx.x, lane = tid & 63, wv = tid >> 6;
  const int wy = wv >> 1, wx = wv & 1;
  const int R0 = blockIdx.x * 64;
  const int C0 = blockIdx.y * 64;
  const int colb = lane & 15, khi = (lane>>4)<<2;

  for (int c = tid; c < 64*32; c += 256){
    int r = c >> 5, c8 = (c & 31) << 3;
    int orow = R0 + r; if (orow > M-1) orow = M-1;
    int bb = orow / RPB; int s = orow - bb*RPB;
    size_t xrow = (size_t)bb*S_TOT + s + OFF;
    *reinterpret_cast<short8v*>(&s_a[r*XPAD + c8]) =
        *reinterpret_cast<const short8v*>(xb + xrow*D_ + c8);
  }
  __syncthreads();

  f32x4 acc[2][2];
  #pragma unroll
  for(int i=0;i<2;++i)
    #pragma unroll
    for(int j=0;j<2;++j) acc[i][j] = (f32x4){0.f,0.f,0.f,0.f};

  const short* ar0 = &s_a[(wy*32 + colb)*XPAD];
  const short* ar1 = ar0 + 16*XPAD;
  const int ntg = (C0 >> 4) + wx*2;
  #pragma unroll
  for (int kt=0; kt<8; ++kt){
    short8v a0 = load_afrag(ar0, kt, khi);
    short8v a1 = load_afrag(ar1, kt, khi);
    short8v b0 = *reinterpret_cast<const short8v*>(Wp + ((size_t)((ntg+0)*8 + kt)*64 + lane)*8);
    short8v b1 = *reinterpret_cast<const short8v*>(Wp + ((size_t)((ntg+1)*8 + kt)*64 + lane)*8);
    acc[0][0] = __builtin_amdgcn_mfma_f32_16x16x32_bf16(a0, b0, acc[0][0], 0,0,0);
    acc[0][1] = __builtin_amdgcn_mfma_f32_16x16x32_bf16(a0, b1, acc[0][1], 0,0,0);
    acc[1][0] = __builtin_amdgcn_mfma_f32_16x16x32_bf16(a1, b0, acc[1][0], 0,0,0);
    acc[1][1] = __builtin_amdgcn_mfma_f32_16x16x32_bf16(a1, b1, acc[1][1], 0,0,0);
  }
  #pragma unroll
  for (int sj=0; sj<2; ++sj){
    int col = C0 + wx*32 + sj*16 + colb;
    float bv = bias[col];
    #pragma unroll
    for (int si=0; si<2; ++si){
      #pragma unroll
      for (int r=0;r<4;++r){
        int orow = R0 + wy*32 + si*16 + ((lane>>4)<<2) + r;
        if (orow < M) outp[(size_t)orow*Nld + col] = silu_f(acc[si][sj][r] + bv);
      }
    }
  }
}

// ---------------- kernel 1c: Z = silu(x@W_Z+b) -> bf16 row-major ------------
__global__ __launch_bounds__(256) void k_gemmZ(
    const short* __restrict__ xb, const short* __restrict__ Wp,
    const float* __restrict__ bias, short* __restrict__ Zb)
{
  __shared__ short s_a[64*XPAD];
  const int tid = threadIdx.x, lane = tid & 63, wv = tid >> 6;
  const int wy = wv >> 1, wx = wv & 1;
  const int R0 = blockIdx.x * 64;
  const int C0 = blockIdx.y * 64;
  const int colb = lane & 15, khi = (lane>>4)<<2;

  for (int c = tid; c < 64*32; c += 256){
    int r = c >> 5, c8 = (c & 31) << 3;
    size_t xrow = (size_t)(R0 + r);
    *reinterpret_cast<short8v*>(&s_a[r*XPAD + c8]) =
        *reinterpret_cast<const short8v*>(xb + xrow*D_ + c8);
  }
  __syncthreads();

  f32x4 acc[2][2];
  #pragma unroll
  for(int i=0;i<2;++i)
    #pragma unroll
    for(int j=0;j<2;++j) acc[i][j] = (f32x4){0.f,0.f,0.f,0.f};

  const short* ar0 = &s_a[(wy*32 + colb)*XPAD];
  const short* ar1 = ar0 + 16*XPAD;
  const int ntg = (C0 >> 4) + wx*2;
  #pragma unroll
  for (int kt=0; kt<8; ++kt){
    short8v a0 = load_afrag(ar0, kt, khi);
    short8v a1 = load_afrag(ar1, kt, khi);
    short8v b0 = *reinterpret_cast<const short8v*>(Wp + ((size_t)((ntg+0)*8 + kt)*64 + lane)*8);
    short8v b1 = *reinterpret_cast<const short8v*>(Wp + ((size_t)((ntg+1)*8 + kt)*64 + lane)*8);
    acc[0][0] = __builtin_amdgcn_mfma_f32_16x16x32_bf16(a0, b0, acc[0][0], 0,0,0);
    acc[0][1] = __builtin_amdgcn_mfma_f32_16x16x32_bf16(a0, b1, acc[0][1], 0,0,0);
    acc[1][0] = __builtin_amdgcn_mfma_f32_16x16x32_bf16(a1, b0, acc[1][0], 0,0,0);
    acc[1][1] = __builtin_amdgcn_mfma_f32_16x16x32_bf16(a1, b1, acc[1][1], 0,0,0);
  }
  #pragma unroll
  for (int sj=0; sj<2; ++sj){
    int col = C0 + wx*32 + sj*16 + colb;
    float bv = bias[col];
    #pragma unroll
    for (int si=0; si<2; ++si){
      #pragma unroll
      for (int r=0;r<4;++r){
        int orow = R0 + wy*32 + si*16 + ((lane>>4)<<2) + r;
        Zb[(size_t)orow*DZ_ + col] = f2bf(silu_f(acc[si][sj][r] + bv));
      }
    }
  }
}

// ---------------- kernel 1d: V -> transposed bf16 Vt[b][512][1088] ----------
__global__ __launch_bounds__(256) void k_gemmV(
    const short* __restrict__ xb, const short* __restrict__ Wp,
    const float* __restrict__ bias, short* __restrict__ Vt)
{
  __shared__ short s_a[64*XPAD];
  __shared__ short s_t[64][72];
  const int tid = threadIdx.x, lane = tid & 63, wv = tid >> 6;
  const int wy = wv >> 1, wx = wv & 1;
  const int R0 = blockIdx.x * 64;     // key base within batch
  const int C0 = blockIdx.y * 64;     // v base
  const int b  = blockIdx.z;
  const int colb = lane & 15, khi = (lane>>4)<<2;

  for (int c = tid; c < 64*32; c += 256){
    int r = c >> 5, c8 = (c & 31) << 3;
    int k = R0 + r; if (k > 1024) k = 1024;
    size_t xrow = (size_t)b*S_TOT + S0_ + k;
    *reinterpret_cast<short8v*>(&s_a[r*XPAD + c8]) =
        *reinterpret_cast<const short8v*>(xb + xrow*D_ + c8);
  }
  __syncthreads();

  f32x4 acc[2][2];
  #pragma unroll
  for(int i=0;i<2;++i)
    #pragma unroll
    for(int j=0;j<2;++j) acc[i][j] = (f32x4){0.f,0.f,0.f,0.f};

  const short* ar0 = &s_a[(wy*32 + colb)*XPAD];
  const short* ar1 = ar0 + 16*XPAD;
  const int ntg = (C0 >> 4) + wx*2;
  #pragma unroll
  for (int kt=0; kt<8; ++kt){
    short8v a0 = load_afrag(ar0, kt, khi);
    short8v a1 = load_afrag(ar1, kt, khi);
    short8v b0 = *reinterpret_cast<const short8v*>(Wp + ((size_t)((ntg+0)*8 + kt)*64 + lane)*8);
    short8v b1 = *reinterpret_cast<const short8v*>(Wp + ((size_t)((ntg+1)*8 + kt)*64 + lane)*8);
    acc[0][0] = __builtin_amdgcn_mfma_f32_16x16x32_bf16(a0, b0, acc[0][0], 0,0,0);
    acc[0][1] = __builtin_amdgcn_mfma_f32_16x16x32_bf16(a0, b1, acc[0][1], 0,0,0);
    acc[1][0] = __builtin_amdgcn_mfma_f32_16x16x32_bf16(a1, b0, acc[1][0], 0,0,0);
    acc[1][1] = __builtin_amdgcn_mfma_f32_16x16x32_bf16(a1, b1, acc[1][1], 0,0,0);
  }
  // silu + transpose into LDS [v][k]
  #pragma unroll
  for (int sj=0; sj<2; ++sj){
    int cl = wx*32 + sj*16 + colb;
    float bv = bias[C0 + cl];
    #pragma unroll
    for (int si=0; si<2; ++si){
      #pragma unroll
      for (int r=0;r<4;++r){
        int rl = wy*32 + si*16 + ((lane>>4)<<2) + r;
        s_t[cl][rl] = f2bf(silu_f(acc[si][sj][r] + bv));
      }
    }
  }
  __syncthreads();
  // coalesced transposed write with zero pad for k >= 1025
  {
    int c = tid >> 2, koff = (tid & 3) * 16;
    short8v v0 = *reinterpret_cast<const short8v*>(&s_t[c][koff]);
    short8v v1 = *reinterpret_cast<const short8v*>(&s_t[c][koff+8]);
    if (R0 + koff + 15 >= S1_){
      #pragma unroll
      for (int e=0;e<8;++e){
        if (R0 + koff + e     >= S1_) v0[e] = 0;
        if (R0 + koff + 8 + e >= S1_) v1[e] = 0;
      }
    }
    size_t o = ((size_t)(b*D2_ + C0 + c))*KPAD + R0 + koff;
    *reinterpret_cast<short8v*>(&Vt[o])   = v0;
    *reinterpret_cast<short8v*>(&Vt[o+8]) = v1;
  }
}

// ---------------- kernel 2: flash attention (swapped-operand MFMA) ----------
// 1 wave/block; block = (batch b, q-tile of 16, v-slice of 128)
__global__ __launch_bounds__(64) void k_flash(
    const short* __restrict__ Zb, const short* __restrict__ Vt,
    const u64* __restrict__ maskb, float* __restrict__ Ub,
    const int* __restrict__ heights,
    const float* __restrict__ os_g, const float* __restrict__ os_b,
    const float* __restrict__ embH)
{
  __shared__ short s_qg[16][132];
  __shared__ float s_qh[16][12];
  __shared__ float s_qb[16];
  __shared__ int   s_hk[KPAD];
  __shared__ u64   s_mb[16][NT_];
  __shared__ float s_scl[16];
  __shared__ float s_linv[16];

  const int lane = threadIdx.x;
  const int b  = blockIdx.x & 7;
  const int i  = blockIdx.x >> 3;
  const int qt = i >> 2, vs = i & 3;
  const int q0 = qt * 16;

  // ---- Q prep: 4 lanes per q-row, 32 dz each
  {
    int row = lane >> 2, part = lane & 3;
    int q = q0 + row; if (q > S0_-1) q = S0_-1;
    const short* zrow = Zb + ((size_t)(b*S_TOT + q))*DZ_ + part*32;
    float qb_acc = 0.f;
    float qh_acc[10];
    #pragma unroll
    for (int h=0;h<10;++h) qh_acc[h] = 0.f;
    #pragma unroll
    for (int e=0; e<32; ++e){
      int dz = part*32 + e;
      float z = bf2f(zrow[e]);
      float Q  = z*os_g[dz]      + os_b[dz];
      float Qp = z*os_g[DZ_+dz]  + os_b[DZ_+dz];
      s_qg[row][dz] = f2bf(Q * os_g[2*DZ_+dz]);
      qb_acc += Q * os_b[2*DZ_+dz];
      #pragma unroll
      for (int h=0;h<10;++h) qh_acc[h] += Qp * embH[h*DZ_ + dz];
    }
    qb_acc += __shfl_xor(qb_acc, 1, 64);
    qb_acc += __shfl_xor(qb_acc, 2, 64);
    #pragma unroll
    for (int h=0;h<10;++h){
      qh_acc[h] += __shfl_xor(qh_acc[h], 1, 64);
      qh_acc[h] += __shfl_xor(qh_acc[h], 2, 64);
    }
    if (part == 0){
      s_qb[row] = qb_acc;
      #pragma unroll
      for (int h=0;h<10;++h) s_qh[row][h] = qh_acc[h];
    }
  }
  for (int k = lane; k < KPAD; k += 64)
    s_hk[k] = (k < S1_) ? heights[b*S_TOT + S0_ + k] : 0;
  for (int idx = lane; idx < 16*NT_; idx += 64){
    int qq = idx / NT_, tt = idx - qq*NT_;
    int qr = q0 + qq; if (qr > S0_-1) qr = S0_-1;
    s_mb[qq][tt] = maskb[((size_t)(b*S0_ + qr))*NT_ + tt];
  }
  __syncthreads();

  const int qcol = lane & 15, grp = lane >> 4;
  const int khi = grp << 2;
  int qme = q0 + qcol; if (qme > S0_-1) qme = S0_-1;
  const int hq = heights[b*S_TOT + qme];
  const float qb = s_qb[qcol];

  // resident Qg B-fragments (col = q = lane&15)
  short8v qgf[4];
  #pragma unroll
  for (int kt=0; kt<4; ++kt) qgf[kt] = load_afrag(&s_qg[qcol][0], kt, khi);

  float m = -1e30f, lsum = 0.f;
  f32x4 O[8];
  #pragma unroll
  for (int vt=0; vt<8; ++vt) O[vt] = (f32x4){0.f,0.f,0.f,0.f};

  const short* zkey = Zb + ((size_t)(b*S_TOT + S0_))*DZ_;
  const short* vbase = Vt + ((size_t)(b*D2_ + vs*128 + qcol))*KPAD;

  for (int t=0; t<NT_; ++t){
    const int kb = t*64;
    // QK^T (swapped): C[key][q]
    f32x4 sc[4];
    #pragma unroll
    for (int st=0; st<4; ++st){
      const short* arow = zkey + (size_t)(kb + st*16 + qcol)*DZ_;
      f32x4 c = (f32x4){0.f,0.f,0.f,0.f};
      #pragma unroll
      for (int kt=0; kt<4; ++kt){
        short8v a = load_afrag(arow, kt, khi);
        c = __builtin_amdgcn_mfma_f32_16x16x32_bf16(a, qgf[kt], c, 0,0,0);
      }
      sc[st] = c;
    }
    // bias + mask
    u64 mb = s_mb[qcol][t];
    float tm = -1e30f;
    #pragma unroll
    for (int st=0; st<4; ++st){
      int4 hk4 = *reinterpret_cast<const int4*>(&s_hk[kb + st*16 + khi]);
      #pragma unroll
      for (int r=0;r<4;++r){
        int hk = (&hk4.x)[r];
        int idx = min(max(hk - hq, 1), 10) - 1;
        float v = (sc[st][r] + qb + s_qh[qcol][idx]) * SCALE_INV;
        int kl = st*16 + khi + r;
        v = ((mb >> kl) & 1ull) ? v : -9999.f;
        sc[st][r] = v;
        tm = fmaxf(tm, v);
      }
    }
    tm = fmaxf(tm, __shfl_xor(tm, 16, 64));
    tm = fmaxf(tm, __shfl_xor(tm, 32, 64));
    // defer-max rescale
    if (!__all(tm <= m + 8.f)){
      float mn = fmaxf(m, tm);
      float scale = __expf(m - mn);
      m = mn;
      lsum *= scale;
      if (lane < 16) s_scl[lane] = scale;
      __builtin_amdgcn_s_waitcnt(0);   // lgkm drain for in-wave LDS visibility
      float s4[4];
      #pragma unroll
      for (int r=0;r<4;++r) s4[r] = s_scl[khi + r];
      #pragma unroll
      for (int vt=0; vt<8; ++vt)
        #pragma unroll
        for (int r=0;r<4;++r) O[vt][r] *= s4[r];
    }
    // p = exp(s-m), tile sum, pack to PV A-frags
    float ls = 0.f;
    #pragma unroll
    for (int st=0; st<4; ++st)
      #pragma unroll
      for (int r=0;r<4;++r){
        float p = __expf(sc[st][r] - m);
        ls += p;
        sc[st][r] = p;
      }
    ls += __shfl_xor(ls, 16, 64);
    ls += __shfl_xor(ls, 32, 64);
    lsum += ls;
    short8v pa[2];
    #pragma unroll
    for (int kt=0; kt<2; ++kt){
      short8v f;
      #pragma unroll
      for (int j=0;j<8;++j) f[j] = f2bf(sc[2*kt + (j>>2)][j&3]);
      pa[kt] = f;
    }
    // PV: O += P @ V  (B-frags from transposed Vt rows)
    #pragma unroll
    for (int vt=0; vt<8; ++vt){
      const short* vrow = vbase + (size_t)(vt*16)*KPAD + kb;
      #pragma unroll
      for (int kt=0; kt<2; ++kt){
        short8v bf = load_afrag(vrow, kt, khi);
        O[vt] = __builtin_amdgcn_mfma_f32_16x16x32_bf16(pa[kt], bf, O[vt], 0,0,0);
      }
    }
  }

  if (lane < 16) s_linv[lane] = 1.f / lsum;
  __syncthreads();
  float li[4];
  #pragma unroll
  for (int r=0;r<4;++r) li[r] = s_linv[khi + r];
  #pragma unroll
  for (int vt=0; vt<8; ++vt){
    #pragma unroll
    for (int r=0;r<4;++r){
      int q = q0 + khi + r;
      if (q < S0_){
        size_t off = ((size_t)(b*S0_ + q))*D2_ + vs*128 + vt*16 + qcol;
        Ub[off] = Ub[off] * O[vt][r] * li[r];
      }
    }
  }
}

// ---------------- kernel 3: fused out-proj + gating (MFMA) ------------------
__global__ __launch_bounds__(256) void k_outg(
    const float* __restrict__ UV, const float* __restrict__ seq,
    const short* __restrict__ Wpo, const float* __restrict__ b_out,
    const short* __restrict__ Wpg, const float* __restrict__ b_gate,
    float* __restrict__ out)
{
  __shared__ short bufA[64*XPAD];
  __shared__ short bufB[64*XPAD];
  const int tid = threadIdx.x, lane = tid & 63, wv = tid >> 6;
  const int R0 = blockIdx.x * 64;
  const int colb = lane & 15, khi = (lane>>4)<<2;

  f32x4 acc_o[16];
  #pragma unroll
  for (int nt=0;nt<16;++nt) acc_o[nt] = (f32x4){0.f,0.f,0.f,0.f};

  const short* arow = &bufA[(wv*16 + colb)*XPAD];

  #pragma unroll
  for (int half=0; half<2; ++half){
    __syncthreads();
    for (int c = tid; c < 64*64; c += 256){
      int r = c >> 6, c4 = (c & 63) << 2;
      int orow = min(R0 + r, 8183);
      float4 f = *reinterpret_cast<const float4*>(UV + (size_t)orow*D2_ + half*256 + c4);
      short4v h = { f2bf(f.x), f2bf(f.y), f2bf(f.z), f2bf(f.w) };
      *reinterpret_cast<short4v*>(&bufA[r*XPAD + c4]) = h;
    }
    __syncthreads();
    #pragma unroll
    for (int kt=0; kt<8; ++kt){
      short8v a = load_afrag(arow, kt, khi);
      #pragma unroll
      for (int nt=0; nt<16; ++nt){
        short8v b = *reinterpret_cast<const short8v*>(Wpo + ((size_t)(nt*16 + half*8 + kt)*64 + lane)*8);
        acc_o[nt] = __builtin_amdgcn_mfma_f32_16x16x32_bf16(a, b, acc_o[nt], 0,0,0);
      }
    }
  }
  #pragma unroll
  for (int nt=0; nt<16; ++nt){
    float bv = b_out[nt*16 + colb];
    #pragma unroll
    for (int r=0;r<4;++r) acc_o[nt][r] += bv;
  }
  __syncthreads();
  #pragma unroll
  for (int nt=0; nt<16; ++nt){
    int col = nt*16 + colb;
    #pragma unroll
    for (int r=0;r<4;++r)
      bufA[(wv*16 + ((lane>>4)<<2) + r)*XPAD + col] = f2bf(acc_o[nt][r]);
  }
  for (int c = tid; c < 64*64; c += 256){
    int r = c >> 6, c4 = (c & 63) << 2;
    int orow = min(R0 + r, 8183);
    int bb = orow / S0_; int s = orow - bb*S0_;
    float4 f = *reinterpret_cast<const float4*>(seq + ((size_t)bb*S_TOT + s)*D_ + c4);
    short4v h = { f2bf(f.x), f2bf(f.y), f2bf(f.z), f2bf(f.w) };
    *reinterpret_cast<short4v*>(&bufB[r*XPAD + c4]) = h;
  }
  __syncthreads();

  f32x4 acc_g[16];
  #pragma unroll
  for (int nt=0;nt<16;++nt) acc_g[nt] = (f32x4){0.f,0.f,0.f,0.f};
  const short* arowB = &bufB[(wv*16 + colb)*XPAD];
  #pragma unroll
  for (int kt=0; kt<8; ++kt){
    short8v a = load_afrag(arow, kt, khi);
    #pragma unroll
    for (int nt=0; nt<16; ++nt){
      short8v b = *reinterpret_cast<const short8v*>(Wpg + ((size_t)(nt*16 + kt)*64 + lane)*8);
      acc_g[nt] = __builtin_amdgcn_mfma_f32_16x16x32_bf16(a, b, acc_g[nt], 0,0,0);
    }
  }
  #pragma unroll
  for (int kt=0; kt<8; ++kt){
    short8v a = load_afrag(arowB, kt, khi);
    #pragma unroll
    for (int nt=0; nt<16; ++nt){
      short8v b = *reinterpret_cast<const short8v*>(Wpg + ((size_t)(nt*16 + 8 + kt)*64 + lane)*8);
      acc_g[nt] = __builtin_amdgcn_mfma_f32_16x16x32_bf16(a, b, acc_g[nt], 0,0,0);
    }
  }
  #pragma unroll
  for (int nt=0; nt<16; ++nt){
    int col = nt*16 + colb;
    float bg = b_gate[col];
    #pragma unroll
    for (int r=0;r<4;++r){
      int orow = R0 + wv*16 + ((lane>>4)<<2) + r;
      if (orow < 8184){
        int bb = orow / S0_; int s = orow - bb*S0_;
        float res = seq[((size_t)bb*S_TOT + s)*D_ + col];
        float g = 1.f/(1.f + __expf(-(acc_g[nt][r] + bg)));
        out[((size_t)bb*S_TOT + s)*D_ + col] = g*acc_o[nt][r] + (1.f-g)*res;
      }
    }
  }
}

// ---------------- kernel 4: passthrough tail rows ---------------------------
__global__ void k_copy(const float* __restrict__ seq, float* __restrict__ out){
  const int per_b = S1_ * (D_/4);
  const int total = NB_ * per_b;
  for (int i = blockIdx.x*blockDim.x + threadIdx.x; i < total; i += gridDim.x*blockDim.x) {
    int b = i / per_b;
    int off = i - b*per_b;
    size_t base = ((size_t)b*S_TOT + S0_) * (size_t)(D_/4);
    reinterpret_cast<float4*>(out)[base + off] =
        reinterpret_cast<const float4*>(seq)[base + off];
  }
}

extern "C" void kernel_launch(void* const* d_in, const int* in_sizes, int n_in,
                              void* d_out, int out_size, void* d_ws, size_t ws_size,
                              hipStream_t stream)
{
  const float* seq    = (const float*)d_in[0];
  const unsigned char* amask = (const unsigned char*)d_in[1];
  const int*   heights= (const int*)d_in[2];
  const float* W_init = (const float*)d_in[3];
  const float* b_init = (const float*)d_in[4];
  const float* ln_g   = (const float*)d_in[5];
  const float* ln_b   = (const float*)d_in[6];
  const float* W_U    = (const float*)d_in[7];
  const float* b_U    = (const float*)d_in[8];
  const float* W_V    = (const float*)d_in[9];
  const float* b_V    = (const float*)d_in[10];
  const float* W_Z    = (const float*)d_in[11];
  const float* b_Z    = (const float*)d_in[12];
  const float* os_g   = (const float*)d_in[13];
  const float* os_b   = (const float*)d_in[14];
  const float* embH   = (const float*)d_in[15];
  const float* W_out  = (const float*)d_in[16];
  const float* b_out  = (const float*)d_in[17];
  const float* W_gate = (const float*)d_in[18];
  const float* b_gate = (const float*)d_in[19];
  float* out = (float*)d_out;

  char* w = (char*)d_ws;
  float* Ub = (float*)w;                 w += (size_t)8184*512*4;        // U, then U*V_
  short* Zb = (short*)w;                 w += (size_t)16512*128*2;       // bf16 Z (+pad rows)
  short* Vt = (short*)w;                 w += (size_t)8*512*KPAD*2;      // transposed V
  short* xb = (short*)w;                 w += (size_t)16384*256*2;
  u64*  maskb = (u64*)w;                 w += (size_t)NB_*S0_*NT_*8;
  short* WpI = (short*)w;                w += (size_t)65536*2;
  short* WpU = (short*)w;                w += (size_t)131072*2;
  short* WpV = (short*)w;                w += (size_t)131072*2;
  short* WpZ = (short*)w;                w += (size_t)32768*2;
  short* WpO = (short*)w;                w += (size_t)131072*2;
  short* WpG = (short*)w;                w += (size_t)131072*2;

  hipLaunchKernelGGL(k_pack, dim3(32), dim3(256), 0, stream, W_init, WpI, 256, 256);
  hipLaunchKernelGGL(k_pack, dim3(64), dim3(256), 0, stream, W_U,   WpU, 256, 512);
  hipLaunchKernelGGL(k_pack, dim3(64), dim3(256), 0, stream, W_V,   WpV, 256, 512);
  hipLaunchKernelGGL(k_pack, dim3(16), dim3(256), 0, stream, W_Z,   WpZ, 256, 128);
  hipLaunchKernelGGL(k_pack, dim3(64), dim3(256), 0, stream, W_out, WpO, 512, 256);
  hipLaunchKernelGGL(k_pack, dim3(64), dim3(256), 0, stream, W_gate,WpG, 512, 256);
  hipLaunchKernelGGL(k_maskpack, dim3((NB_*S0_*NT_ + 3)/4), dim3(256), 0, stream, amask, maskb);

  hipLaunchKernelGGL(k_x, dim3(256), dim3(256), 0, stream,
      seq, WpI, b_init, ln_g, ln_b, xb);

  hipLaunchKernelGGL(k_gemm, dim3(128, 8), dim3(256), 0, stream,
      xb, WpU, b_U, Ub, 8184, 1023, 0, 512);
  hipLaunchKernelGGL(k_gemmZ, dim3(256, 2), dim3(256), 0, stream,
      xb, WpZ, b_Z, Zb);
  hipLaunchKernelGGL(k_gemmV, dim3(17, 8, 8), dim3(256), 0, stream,
      xb, WpV, b_V, Vt);

  hipLaunchKernelGGL(k_flash, dim3(2048), dim3(64), 0, stream,
      Zb, Vt, maskb, Ub, heights, os_g, os_b, embH);

  hipLaunchKernelGGL(k_outg, dim3(128), dim3(256), 0, stream,
      Ub, seq, WpO, b_out, WpG, b_gate, out);

  hipLaunchKernelGGL(k_copy, dim3(512), dim3(256), 0, stream, seq, out);
}

// Round 4
// 234.449 us; speedup vs baseline: 4.0182x; 1.9634x over previous
//
#include <hip/hip_runtime.h>
#include <cstdint>
#include <cstddef>

#define S_TOT 2048
#define S0_   1023
#define S1_   1025
#define D_    256
#define D2_   512
#define DZ_   128
#define NB_   8
#define NT_   17            // 17 * 64 padded keys = 1088
#define KT16_ 68            // 17*4 16-key groups
#define SCALE_INV (1.0f/16.0f)
#define XPAD  264           // 256 + 8 bf16 pad

typedef __attribute__((ext_vector_type(8))) short short8v;
typedef __attribute__((ext_vector_type(4))) short short4v;
typedef __attribute__((ext_vector_type(4))) float f32x4;
typedef unsigned long long u64;

__device__ __forceinline__ short f2bf(float f){
  unsigned u = __float_as_uint(f);
  unsigned r = (u + 0x7FFFu + ((u >> 16) & 1u)) >> 16;
  return (short)r;
}
__device__ __forceinline__ float bf2f(short s){
  return __uint_as_float(((unsigned)(unsigned short)s) << 16);
}
__device__ __forceinline__ float silu_f(float x){ return x / (1.f + __expf(-x)); }

// A/B fragment load from a row-major row (verified layout, round 1):
// elems 0..3: k = kt*32 + khi + j ; elems 4..7: +16
__device__ __forceinline__ short8v load_afrag(const short* arow, int kt, int khi){
  short4v lo = *reinterpret_cast<const short4v*>(arow + kt*32 + khi);
  short4v hi = *reinterpret_cast<const short4v*>(arow + kt*32 + khi + 16);
  short8v r = {lo[0],lo[1],lo[2],lo[3],hi[0],hi[1],hi[2],hi[3]};
  return r;
}

// ---------------- weight pack: fp32 (K,N) -> bf16 MFMA-B-fragment order -----
__global__ __launch_bounds__(256) void k_pack(const float* __restrict__ W,
                                              short* __restrict__ dst,
                                              int K, int N){
  const int wv = threadIdx.x >> 6, lane = threadIdx.x & 63;
  const int KT = K >> 5, NT = N >> 4;
  const int tile = blockIdx.x*4 + wv;
  if (tile >= KT*NT) return;
  const int nt = tile / KT, kt = tile - nt*KT;
  const int n = nt*16 + (lane & 15);
  const int kbase = kt*32 + ((lane>>4)<<2);
  short8v v;
  #pragma unroll
  for (int j=0;j<8;++j){
    int k = kbase + (j&3) + ((j>>2)<<4);
    v[j] = f2bf(W[(size_t)k*N + n]);
  }
  *reinterpret_cast<short8v*>(dst + ((size_t)tile*64 + lane)*8) = v;
}

// ---------------- mask pack: bool bytes -> u64 bitmask per 64-key tile ------
__global__ __launch_bounds__(256) void k_maskpack(const unsigned char* __restrict__ amask,
                                                  u64* __restrict__ maskb){
  const int lane = threadIdx.x & 63;
  const int w = blockIdx.x*4 + (threadIdx.x >> 6);
  if (w >= NB_*S0_*NT_) return;
  int b = w / (S0_*NT_);
  int rem = w - b*(S0_*NT_);
  int q = rem / NT_;
  int t = rem - q*NT_;
  int key = t*64 + lane;
  unsigned char v = 0;
  if (key < S1_) v = amask[((size_t)(b*S_TOT + q))*S_TOT + S0_ + key];
  u64 bits = __ballot(v != 0);
  if (lane == 0) maskb[w] = bits;
}

// ---------------- kernel 1a: x = LN(seq@W_init + b) -> bf16 -----------------
__global__ __launch_bounds__(256) void k_x(
    const float* __restrict__ seq, const short* __restrict__ Wp,
    const float* __restrict__ b_init,
    const float* __restrict__ ln_g, const float* __restrict__ ln_b,
    short* __restrict__ xb)
{
  __shared__ short s_a[64*XPAD];
  const int tid = threadIdx.x, lane = tid & 63, wv = tid >> 6;
  const int R0 = blockIdx.x * 64;
  const int colb = lane & 15, khi = (lane>>4)<<2;

  for (int c = tid; c < 64*64; c += 256){
    int row = c >> 6, c4 = (c & 63) << 2;
    float4 f = *reinterpret_cast<const float4*>(seq + (size_t)(R0+row)*D_ + c4);
    short4v h = { f2bf(f.x), f2bf(f.y), f2bf(f.z), f2bf(f.w) };
    *reinterpret_cast<short4v*>(&s_a[row*XPAD + c4]) = h;
  }
  __syncthreads();

  f32x4 acc[16];
  #pragma unroll
  for (int nt=0;nt<16;++nt) acc[nt] = (f32x4){0.f,0.f,0.f,0.f};

  const short* arow = &s_a[(wv*16 + colb)*XPAD];
  #pragma unroll
  for (int kt=0; kt<8; ++kt){
    short8v a = load_afrag(arow, kt, khi);
    #pragma unroll
    for (int nt=0; nt<16; ++nt){
      short8v b = *reinterpret_cast<const short8v*>(Wp + ((size_t)(nt*8 + kt)*64 + lane)*8);
      acc[nt] = __builtin_amdgcn_mfma_f32_16x16x32_bf16(a, b, acc[nt], 0, 0, 0);
    }
  }

  float sum[4] = {0.f,0.f,0.f,0.f};
  #pragma unroll
  for (int nt=0; nt<16; ++nt){
    float bv = b_init[nt*16 + colb];
    #pragma unroll
    for (int r=0;r<4;++r){ acc[nt][r] += bv; sum[r] += acc[nt][r]; }
  }
  #pragma unroll
  for (int r=0;r<4;++r){
    #pragma unroll
    for (int m=1;m<16;m<<=1) sum[r] += __shfl_xor(sum[r], m, 64);
    sum[r] *= (1.f/256.f);
  }
  float var[4] = {0.f,0.f,0.f,0.f};
  #pragma unroll
  for (int nt=0; nt<16; ++nt)
    #pragma unroll
    for (int r=0;r<4;++r){ float d = acc[nt][r]-sum[r]; var[r] += d*d; }
  #pragma unroll
  for (int r=0;r<4;++r){
    #pragma unroll
    for (int m=1;m<16;m<<=1) var[r] += __shfl_xor(var[r], m, 64);
    var[r] = rsqrtf(var[r]*(1.f/256.f) + 1e-5f);
  }
  #pragma unroll
  for (int nt=0; nt<16; ++nt){
    int col = nt*16 + colb;
    float g = ln_g[col], bb = ln_b[col];
    #pragma unroll
    for (int r=0;r<4;++r){
      float xn = (acc[nt][r]-sum[r])*var[r]*g + bb;
      s_a[(wv*16 + ((lane>>4)<<2) + r)*XPAD + col] = f2bf(xn);
    }
  }
  __syncthreads();
  for (int c = tid; c < 64*32; c += 256){
    int row = c >> 5, c8 = (c & 31) << 3;
    *reinterpret_cast<short8v*>(xb + (size_t)(R0+row)*D_ + c8) =
        *reinterpret_cast<const short8v*>(&s_a[row*XPAD + c8]);
  }
}

// ---------------- kernel 1b: U = silu(x@W+b), fp32 out ---------------------
__global__ __launch_bounds__(256) void k_gemm(
    const short* __restrict__ xb, const short* __restrict__ Wp,
    const float* __restrict__ bias, float* __restrict__ outp,
    int M, int RPB, int OFF, int Nld)
{
  __shared__ short s_a[64*XPAD];
  const int tid = threadIdx.x, lane = tid & 63, wv = tid >> 6;
  const int wy = wv >> 1, wx = wv & 1;
  const int R0 = blockIdx.x * 64;
  const int C0 = blockIdx.y * 64;
  const int colb = lane & 15, khi = (lane>>4)<<2;

  for (int c = tid; c < 64*32; c += 256){
    int r = c >> 5, c8 = (c & 31) << 3;
    int orow = R0 + r; if (orow > M-1) orow = M-1;
    int bb = orow / RPB; int s = orow - bb*RPB;
    size_t xrow = (size_t)bb*S_TOT + s + OFF;
    *reinterpret_cast<short8v*>(&s_a[r*XPAD + c8]) =
        *reinterpret_cast<const short8v*>(xb + xrow*D_ + c8);
  }
  __syncthreads();

  f32x4 acc[2][2];
  #pragma unroll
  for(int i=0;i<2;++i)
    #pragma unroll
    for(int j=0;j<2;++j) acc[i][j] = (f32x4){0.f,0.f,0.f,0.f};

  const short* ar0 = &s_a[(wy*32 + colb)*XPAD];
  const short* ar1 = ar0 + 16*XPAD;
  const int ntg = (C0 >> 4) + wx*2;
  #pragma unroll
  for (int kt=0; kt<8; ++kt){
    short8v a0 = load_afrag(ar0, kt, khi);
    short8v a1 = load_afrag(ar1, kt, khi);
    short8v b0 = *reinterpret_cast<const short8v*>(Wp + ((size_t)((ntg+0)*8 + kt)*64 + lane)*8);
    short8v b1 = *reinterpret_cast<const short8v*>(Wp + ((size_t)((ntg+1)*8 + kt)*64 + lane)*8);
    acc[0][0] = __builtin_amdgcn_mfma_f32_16x16x32_bf16(a0, b0, acc[0][0], 0,0,0);
    acc[0][1] = __builtin_amdgcn_mfma_f32_16x16x32_bf16(a0, b1, acc[0][1], 0,0,0);
    acc[1][0] = __builtin_amdgcn_mfma_f32_16x16x32_bf16(a1, b0, acc[1][0], 0,0,0);
    acc[1][1] = __builtin_amdgcn_mfma_f32_16x16x32_bf16(a1, b1, acc[1][1], 0,0,0);
  }
  #pragma unroll
  for (int sj=0; sj<2; ++sj){
    int col = C0 + wx*32 + sj*16 + colb;
    float bv = bias[col];
    #pragma unroll
    for (int si=0; si<2; ++si){
      #pragma unroll
      for (int r=0;r<4;++r){
        int orow = R0 + wy*32 + si*16 + ((lane>>4)<<2) + r;
        if (orow < M) outp[(size_t)orow*Nld + col] = silu_f(acc[si][sj][r] + bv);
      }
    }
  }
}

// ---------------- kernel 1c: Z = silu(x@W_Z+b) -> bf16 row-major ------------
__global__ __launch_bounds__(256) void k_gemmZ(
    const short* __restrict__ xb, const short* __restrict__ Wp,
    const float* __restrict__ bias, short* __restrict__ Zb)
{
  __shared__ short s_a[64*XPAD];
  const int tid = threadIdx.x, lane = tid & 63, wv = tid >> 6;
  const int wy = wv >> 1, wx = wv & 1;
  const int R0 = blockIdx.x * 64;
  const int C0 = blockIdx.y * 64;
  const int colb = lane & 15, khi = (lane>>4)<<2;

  for (int c = tid; c < 64*32; c += 256){
    int r = c >> 5, c8 = (c & 31) << 3;
    size_t xrow = (size_t)(R0 + r);
    *reinterpret_cast<short8v*>(&s_a[r*XPAD + c8]) =
        *reinterpret_cast<const short8v*>(xb + xrow*D_ + c8);
  }
  __syncthreads();

  f32x4 acc[2][2];
  #pragma unroll
  for(int i=0;i<2;++i)
    #pragma unroll
    for(int j=0;j<2;++j) acc[i][j] = (f32x4){0.f,0.f,0.f,0.f};

  const short* ar0 = &s_a[(wy*32 + colb)*XPAD];
  const short* ar1 = ar0 + 16*XPAD;
  const int ntg = (C0 >> 4) + wx*2;
  #pragma unroll
  for (int kt=0; kt<8; ++kt){
    short8v a0 = load_afrag(ar0, kt, khi);
    short8v a1 = load_afrag(ar1, kt, khi);
    short8v b0 = *reinterpret_cast<const short8v*>(Wp + ((size_t)((ntg+0)*8 + kt)*64 + lane)*8);
    short8v b1 = *reinterpret_cast<const short8v*>(Wp + ((size_t)((ntg+1)*8 + kt)*64 + lane)*8);
    acc[0][0] = __builtin_amdgcn_mfma_f32_16x16x32_bf16(a0, b0, acc[0][0], 0,0,0);
    acc[0][1] = __builtin_amdgcn_mfma_f32_16x16x32_bf16(a0, b1, acc[0][1], 0,0,0);
    acc[1][0] = __builtin_amdgcn_mfma_f32_16x16x32_bf16(a1, b0, acc[1][0], 0,0,0);
    acc[1][1] = __builtin_amdgcn_mfma_f32_16x16x32_bf16(a1, b1, acc[1][1], 0,0,0);
  }
  #pragma unroll
  for (int sj=0; sj<2; ++sj){
    int col = C0 + wx*32 + sj*16 + colb;
    float bv = bias[col];
    #pragma unroll
    for (int si=0; si<2; ++si){
      #pragma unroll
      for (int r=0;r<4;++r){
        int orow = R0 + wy*32 + si*16 + ((lane>>4)<<2) + r;
        Zb[(size_t)orow*DZ_ + col] = f2bf(silu_f(acc[si][sj][r] + bv));
      }
    }
  }
}

// ------- kernel 1c2: pack Z key rows -> A-fragment order (for flash QK) -----
// ZkF[(b*KT16_ + kt16)*4 + kt][64][8]; elem j of lane l =
//   Z[key = kt16*16 + (l&15)][dz = kt*32 + (l>>4)*4 + (j&3) + 16*(j>>2)]
__global__ __launch_bounds__(256) void k_packZ(const short* __restrict__ Zb,
                                               short* __restrict__ ZkF){
  const int lane = threadIdx.x & 63;
  const int w = blockIdx.x*4 + (threadIdx.x >> 6);
  if (w >= NB_*KT16_*4) return;
  const int b = w / (KT16_*4);
  const int rem = w - b*(KT16_*4);
  const int kt16 = rem >> 2, kt = rem & 3;
  int key = kt16*16 + (lane & 15); if (key > 1024) key = 1024;
  const short* zr = Zb + ((size_t)(b*S_TOT + S0_ + key))*DZ_ + kt*32 + ((lane>>4)<<2);
  short4v lo = *reinterpret_cast<const short4v*>(zr);
  short4v hi = *reinterpret_cast<const short4v*>(zr + 16);
  short8v f = {lo[0],lo[1],lo[2],lo[3],hi[0],hi[1],hi[2],hi[3]};
  *reinterpret_cast<short8v*>(ZkF + ((size_t)w*64 + lane)*8) = f;
}

// ---------------- kernel 1d: V -> bf16 B-fragment order VtF -----------------
// VtF[((b*32 + nt)*2*NT_ + k2)][64][8]: B-frag for v-tile nt, key-subtile k2
__global__ __launch_bounds__(256) void k_gemmV(
    const short* __restrict__ xb, const short* __restrict__ Wp,
    const float* __restrict__ bias, short* __restrict__ VtF)
{
  __shared__ short s_a[64*XPAD];
  __shared__ short s_t[64][72];
  const int tid = threadIdx.x, lane = tid & 63, wv = tid >> 6;
  const int wy = wv >> 1, wx = wv & 1;
  const int R0 = blockIdx.x * 64;     // key base within batch (tile t = R0/64)
  const int C0 = blockIdx.y * 64;     // v base
  const int b  = blockIdx.z;
  const int colb = lane & 15, khi = (lane>>4)<<2;

  for (int c = tid; c < 64*32; c += 256){
    int r = c >> 5, c8 = (c & 31) << 3;
    int k = R0 + r; if (k > 1024) k = 1024;
    size_t xrow = (size_t)b*S_TOT + S0_ + k;
    *reinterpret_cast<short8v*>(&s_a[r*XPAD + c8]) =
        *reinterpret_cast<const short8v*>(xb + xrow*D_ + c8);
  }
  __syncthreads();

  f32x4 acc[2][2];
  #pragma unroll
  for(int i=0;i<2;++i)
    #pragma unroll
    for(int j=0;j<2;++j) acc[i][j] = (f32x4){0.f,0.f,0.f,0.f};

  const short* ar0 = &s_a[(wy*32 + colb)*XPAD];
  const short* ar1 = ar0 + 16*XPAD;
  const int ntg = (C0 >> 4) + wx*2;
  #pragma unroll
  for (int kt=0; kt<8; ++kt){
    short8v a0 = load_afrag(ar0, kt, khi);
    short8v a1 = load_afrag(ar1, kt, khi);
    short8v b0 = *reinterpret_cast<const short8v*>(Wp + ((size_t)((ntg+0)*8 + kt)*64 + lane)*8);
    short8v b1 = *reinterpret_cast<const short8v*>(Wp + ((size_t)((ntg+1)*8 + kt)*64 + lane)*8);
    acc[0][0] = __builtin_amdgcn_mfma_f32_16x16x32_bf16(a0, b0, acc[0][0], 0,0,0);
    acc[0][1] = __builtin_amdgcn_mfma_f32_16x16x32_bf16(a0, b1, acc[0][1], 0,0,0);
    acc[1][0] = __builtin_amdgcn_mfma_f32_16x16x32_bf16(a1, b0, acc[1][0], 0,0,0);
    acc[1][1] = __builtin_amdgcn_mfma_f32_16x16x32_bf16(a1, b1, acc[1][1], 0,0,0);
  }
  // silu + transpose into LDS [v_local][key_local]
  #pragma unroll
  for (int sj=0; sj<2; ++sj){
    int cl = wx*32 + sj*16 + colb;
    float bv = bias[C0 + cl];
    #pragma unroll
    for (int si=0; si<2; ++si){
      #pragma unroll
      for (int r=0;r<4;++r){
        int rl = wy*32 + si*16 + ((lane>>4)<<2) + r;
        s_t[cl][rl] = f2bf(silu_f(acc[si][sj][r] + bv));
      }
    }
  }
  __syncthreads();
  // emit B-fragments (zero pad for key >= S1_)
  {
    const int vt_l = tid >> 6;           // 0..3: v-tile within C0
    const int vloc = vt_l*16 + (lane & 15);
    const int krow = (lane>>4)<<2;
    const int t = R0 >> 6;
    #pragma unroll
    for (int kt=0; kt<2; ++kt){
      short8v f;
      #pragma unroll
      for (int j=0;j<8;++j){
        int kl = kt*32 + krow + (j&3) + ((j>>2)<<4);
        short v = s_t[vloc][kl];
        if (R0 + kl >= S1_) v = 0;
        f[j] = v;
      }
      size_t o = (((size_t)b*32 + (C0>>4) + vt_l)*(2*NT_) + 2*t + kt)*64 + lane;
      *reinterpret_cast<short8v*>(VtF + o*8) = f;
    }
  }
}

// ---------------- kernel 2: flash attention, 4 cooperating waves ------------
// block = (batch b, q-tile of 16); wave wv owns v-slice wv*128..+127
__global__ __launch_bounds__(256,2) void k_flash(
    const short* __restrict__ Zb, const short* __restrict__ ZkF,
    const short* __restrict__ VtF, const u64* __restrict__ maskb,
    float* __restrict__ Ub, const int* __restrict__ heights,
    const float* __restrict__ os_g, const float* __restrict__ os_b,
    const float* __restrict__ embH)
{
  __shared__ short  s_qg[16][132];
  __shared__ float  s_qh[16][12];
  __shared__ float  s_qb[16];
  __shared__ int    s_hk[NT_*64];
  __shared__ u64    s_mb[16][NT_];
  __shared__ float  s_mx[2][4][16];
  __shared__ float  s_sm[2][4][16];
  __shared__ short8v s_pl[8][64];   // [buf*4 + tile][lane]
  __shared__ short8v s_ph[8][64];

  const int tid = threadIdx.x, lane = tid & 63, wv = tid >> 6;
  const int b  = blockIdx.x & 7;
  const int qt = blockIdx.x >> 3;
  const int q0 = qt * 16;

  // ---- Q prep: 16 threads per q-row, 8 dz each
  {
    int row = tid >> 4, part = tid & 15;
    int q = q0 + row; if (q > S0_-1) q = S0_-1;
    const short* zrow = Zb + ((size_t)(b*S_TOT + q))*DZ_ + part*8;
    float qb_acc = 0.f;
    float qh_acc[10];
    #pragma unroll
    for (int h=0;h<10;++h) qh_acc[h] = 0.f;
    #pragma unroll
    for (int e=0; e<8; ++e){
      int dz = part*8 + e;
      float z = bf2f(zrow[e]);
      float Q  = z*os_g[dz]      + os_b[dz];
      float Qp = z*os_g[DZ_+dz]  + os_b[DZ_+dz];
      s_qg[row][dz] = f2bf(Q * os_g[2*DZ_+dz]);
      qb_acc += Q * os_b[2*DZ_+dz];
      #pragma unroll
      for (int h=0;h<10;++h) qh_acc[h] += Qp * embH[h*DZ_ + dz];
    }
    #pragma unroll
    for (int m=1;m<16;m<<=1){
      qb_acc += __shfl_xor(qb_acc, m, 64);
      #pragma unroll
      for (int h=0;h<10;++h) qh_acc[h] += __shfl_xor(qh_acc[h], m, 64);
    }
    if (part == 0){
      s_qb[row] = qb_acc;
      #pragma unroll
      for (int h=0;h<10;++h) s_qh[row][h] = qh_acc[h];
    }
  }
  for (int k = tid; k < NT_*64; k += 256)
    s_hk[k] = (k < S1_) ? heights[b*S_TOT + S0_ + k] : 0;
  for (int idx = tid; idx < 16*NT_; idx += 256){
    int qq = idx / NT_, tt = idx - qq*NT_;
    int qr = q0 + qq; if (qr > S0_-1) qr = S0_-1;
    s_mb[qq][tt] = maskb[((size_t)(b*S0_ + qr))*NT_ + tt];
  }
  __syncthreads();

  const int qcol = lane & 15, khi = (lane>>4)<<2;
  int qme = q0 + qcol; if (qme > S0_-1) qme = S0_-1;
  const int hq = heights[b*S_TOT + qme];
  const float qb = s_qb[qcol];

  short8v qgf[4];
  #pragma unroll
  for (int kt=0; kt<4; ++kt) qgf[kt] = load_afrag(&s_qg[qcol][0], kt, khi);

  float mcol = -1e30f;
  float mrow[4] = {-1e30f,-1e30f,-1e30f,-1e30f};
  float lrow[4] = {0.f,0.f,0.f,0.f};
  f32x4 O[8];
  #pragma unroll
  for (int vt=0; vt<8; ++vt) O[vt] = (f32x4){0.f,0.f,0.f,0.f};

  int buf = 0;
  for (int it=0; it<5; ++it){
    const int t = it*4 + wv;
    const bool tvalid = (t < NT_);
    f32x4 sc[4];
    float tm = -1e30f;
    // ---- phase A: own tile's QK^T + bias + mask
    if (tvalid){
      #pragma unroll
      for (int st=0; st<4; ++st){
        f32x4 c = (f32x4){0.f,0.f,0.f,0.f};
        #pragma unroll
        for (int kt=0; kt<4; ++kt){
          short8v a = *reinterpret_cast<const short8v*>(
              ZkF + (((size_t)(b*KT16_ + t*4 + st)*4 + kt)*64 + lane)*8);
          c = __builtin_amdgcn_mfma_f32_16x16x32_bf16(a, qgf[kt], c, 0,0,0);
        }
        sc[st] = c;
      }
      u64 mb = s_mb[qcol][t];
      #pragma unroll
      for (int st=0; st<4; ++st){
        int4 hk4 = *reinterpret_cast<const int4*>(&s_hk[t*64 + st*16 + khi]);
        #pragma unroll
        for (int r=0;r<4;++r){
          int hk = (&hk4.x)[r];
          int idx = min(max(hk - hq, 1), 10) - 1;
          float v = (sc[st][r] + qb + s_qh[qcol][idx]) * SCALE_INV;
          int kl = st*16 + khi + r;
          v = ((mb >> kl) & 1ull) ? v : -9999.f;
          sc[st][r] = v;
          tm = fmaxf(tm, v);
        }
      }
      tm = fmaxf(tm, __shfl_xor(tm, 16, 64));
      tm = fmaxf(tm, __shfl_xor(tm, 32, 64));
    }
    if (lane < 16) s_mx[buf][wv][lane] = tm;
    __syncthreads();

    // ---- phase B: combined max, defer-max rescale, exp, pack P
    float cmc = fmaxf(fmaxf(s_mx[buf][0][qcol], s_mx[buf][1][qcol]),
                      fmaxf(s_mx[buf][2][qcol], s_mx[buf][3][qcol]));
    if (__any(cmc > mcol + 8.f)){
      mcol = fmaxf(mcol, cmc);
      #pragma unroll
      for (int r=0;r<4;++r){
        int qr = khi + r;
        float cmr = fmaxf(fmaxf(s_mx[buf][0][qr], s_mx[buf][1][qr]),
                          fmaxf(s_mx[buf][2][qr], s_mx[buf][3][qr]));
        float mn = fmaxf(mrow[r], cmr);
        float s = __expf(mrow[r] - mn);
        lrow[r] *= s; mrow[r] = mn;
        #pragma unroll
        for (int vt=0; vt<8; ++vt) O[vt][r] *= s;
      }
    }
    float ls = 0.f;
    if (tvalid){
      #pragma unroll
      for (int st=0; st<4; ++st)
        #pragma unroll
        for (int r=0;r<4;++r){
          float p = __expf(sc[st][r] - mcol);
          ls += p; sc[st][r] = p;
        }
    }
    ls += __shfl_xor(ls, 16, 64);
    ls += __shfl_xor(ls, 32, 64);
    if (lane < 16) s_sm[buf][wv][lane] = ls;
    if (tvalid){
      short8v pa0, pa1;
      #pragma unroll
      for (int j=0;j<8;++j){
        pa0[j] = f2bf(sc[(j>>2)][j&3]);
        pa1[j] = f2bf(sc[2 + (j>>2)][j&3]);
      }
      s_pl[buf*4 + wv][lane] = pa0;
      s_ph[buf*4 + wv][lane] = pa1;
    }
    __syncthreads();

    // ---- phase C: accumulate l; PV over the 4 tiles for own v-slice
    #pragma unroll
    for (int r=0;r<4;++r){
      int qr = khi + r;
      lrow[r] += s_sm[buf][0][qr] + s_sm[buf][1][qr] + s_sm[buf][2][qr] + s_sm[buf][3][qr];
    }
    #pragma unroll
    for (int tw=0; tw<4; ++tw){
      int tl = it*4 + tw;
      if (tl >= NT_) break;
      short8v pa0 = s_pl[buf*4 + tw][lane];
      short8v pa1 = s_ph[buf*4 + tw][lane];
      #pragma unroll
      for (int vt=0; vt<8; ++vt){
        size_t vb = ((size_t)b*32 + wv*8 + vt)*(2*NT_) + 2*tl;
        short8v b0 = *reinterpret_cast<const short8v*>(VtF + (vb*64 + lane)*8);
        short8v b1 = *reinterpret_cast<const short8v*>(VtF + ((vb+1)*64 + lane)*8);
        O[vt] = __builtin_amdgcn_mfma_f32_16x16x32_bf16(pa0, b0, O[vt], 0,0,0);
        O[vt] = __builtin_amdgcn_mfma_f32_16x16x32_bf16(pa1, b1, O[vt], 0,0,0);
      }
    }
    buf ^= 1;
  }

  // ---- epilogue: U *= O / l
  #pragma unroll
  for (int r=0;r<4;++r){
    int q = q0 + khi + r;
    if (q < S0_){
      float inv = 1.f / lrow[r];
      #pragma unroll
      for (int vt=0; vt<8; ++vt){
        size_t off = ((size_t)(b*S0_ + q))*D2_ + wv*128 + vt*16 + qcol;
        Ub[off] = Ub[off] * O[vt][r] * inv;
      }
    }
  }
}

// ---------------- kernel 3: fused out-proj + gating (MFMA) ------------------
__global__ __launch_bounds__(256) void k_outg(
    const float* __restrict__ UV, const float* __restrict__ seq,
    const short* __restrict__ Wpo, const float* __restrict__ b_out,
    const short* __restrict__ Wpg, const float* __restrict__ b_gate,
    float* __restrict__ out)
{
  __shared__ short bufA[64*XPAD];
  __shared__ short bufB[64*XPAD];
  const int tid = threadIdx.x, lane = tid & 63, wv = tid >> 6;
  const int R0 = blockIdx.x * 64;
  const int colb = lane & 15, khi = (lane>>4)<<2;

  f32x4 acc_o[16];
  #pragma unroll
  for (int nt=0;nt<16;++nt) acc_o[nt] = (f32x4){0.f,0.f,0.f,0.f};

  const short* arow = &bufA[(wv*16 + colb)*XPAD];

  #pragma unroll
  for (int half=0; half<2; ++half){
    __syncthreads();
    for (int c = tid; c < 64*64; c += 256){
      int r = c >> 6, c4 = (c & 63) << 2;
      int orow = min(R0 + r, 8183);
      float4 f = *reinterpret_cast<const float4*>(UV + (size_t)orow*D2_ + half*256 + c4);
      short4v h = { f2bf(f.x), f2bf(f.y), f2bf(f.z), f2bf(f.w) };
      *reinterpret_cast<short4v*>(&bufA[r*XPAD + c4]) = h;
    }
    __syncthreads();
    #pragma unroll
    for (int kt=0; kt<8; ++kt){
      short8v a = load_afrag(arow, kt, khi);
      #pragma unroll
      for (int nt=0; nt<16; ++nt){
        short8v b = *reinterpret_cast<const short8v*>(Wpo + ((size_t)(nt*16 + half*8 + kt)*64 + lane)*8);
        acc_o[nt] = __builtin_amdgcn_mfma_f32_16x16x32_bf16(a, b, acc_o[nt], 0,0,0);
      }
    }
  }
  #pragma unroll
  for (int nt=0; nt<16; ++nt){
    float bv = b_out[nt*16 + colb];
    #pragma unroll
    for (int r=0;r<4;++r) acc_o[nt][r] += bv;
  }
  __syncthreads();
  #pragma unroll
  for (int nt=0; nt<16; ++nt){
    int col = nt*16 + colb;
    #pragma unroll
    for (int r=0;r<4;++r)
      bufA[(wv*16 + ((lane>>4)<<2) + r)*XPAD + col] = f2bf(acc_o[nt][r]);
  }
  for (int c = tid; c < 64*64; c += 256){
    int r = c >> 6, c4 = (c & 63) << 2;
    int orow = min(R0 + r, 8183);
    int bb = orow / S0_; int s = orow - bb*S0_;
    float4 f = *reinterpret_cast<const float4*>(seq + ((size_t)bb*S_TOT + s)*D_ + c4);
    short4v h = { f2bf(f.x), f2bf(f.y), f2bf(f.z), f2bf(f.w) };
    *reinterpret_cast<short4v*>(&bufB[r*XPAD + c4]) = h;
  }
  __syncthreads();

  f32x4 acc_g[16];
  #pragma unroll
  for (int nt=0;nt<16;++nt) acc_g[nt] = (f32x4){0.f,0.f,0.f,0.f};
  const short* arowB = &bufB[(wv*16 + colb)*XPAD];
  #pragma unroll
  for (int kt=0; kt<8; ++kt){
    short8v a = load_afrag(arow, kt, khi);
    #pragma unroll
    for (int nt=0; nt<16; ++nt){
      short8v b = *reinterpret_cast<const short8v*>(Wpg + ((size_t)(nt*16 + kt)*64 + lane)*8);
      acc_g[nt] = __builtin_amdgcn_mfma_f32_16x16x32_bf16(a, b, acc_g[nt], 0,0,0);
    }
  }
  #pragma unroll
  for (int kt=0; kt<8; ++kt){
    short8v a = load_afrag(arowB, kt, khi);
    #pragma unroll
    for (int nt=0; nt<16; ++nt){
      short8v b = *reinterpret_cast<const short8v*>(Wpg + ((size_t)(nt*16 + 8 + kt)*64 + lane)*8);
      acc_g[nt] = __builtin_amdgcn_mfma_f32_16x16x32_bf16(a, b, acc_g[nt], 0,0,0);
    }
  }
  #pragma unroll
  for (int nt=0; nt<16; ++nt){
    int col = nt*16 + colb;
    float bg = b_gate[col];
    #pragma unroll
    for (int r=0;r<4;++r){
      int orow = R0 + wv*16 + ((lane>>4)<<2) + r;
      if (orow < 8184){
        int bb = orow / S0_; int s = orow - bb*S0_;
        float res = seq[((size_t)bb*S_TOT + s)*D_ + col];
        float g = 1.f/(1.f + __expf(-(acc_g[nt][r] + bg)));
        out[((size_t)bb*S_TOT + s)*D_ + col] = g*acc_o[nt][r] + (1.f-g)*res;
      }
    }
  }
}

// ---------------- kernel 4: passthrough tail rows ---------------------------
__global__ void k_copy(const float* __restrict__ seq, float* __restrict__ out){
  const int per_b = S1_ * (D_/4);
  const int total = NB_ * per_b;
  for (int i = blockIdx.x*blockDim.x + threadIdx.x; i < total; i += gridDim.x*blockDim.x) {
    int b = i / per_b;
    int off = i - b*per_b;
    size_t base = ((size_t)b*S_TOT + S0_) * (size_t)(D_/4);
    reinterpret_cast<float4*>(out)[base + off] =
        reinterpret_cast<const float4*>(seq)[base + off];
  }
}

extern "C" void kernel_launch(void* const* d_in, const int* in_sizes, int n_in,
                              void* d_out, int out_size, void* d_ws, size_t ws_size,
                              hipStream_t stream)
{
  const float* seq    = (const float*)d_in[0];
  const unsigned char* amask = (const unsigned char*)d_in[1];
  const int*   heights= (const int*)d_in[2];
  const float* W_init = (const float*)d_in[3];
  const float* b_init = (const float*)d_in[4];
  const float* ln_g   = (const float*)d_in[5];
  const float* ln_b   = (const float*)d_in[6];
  const float* W_U    = (const float*)d_in[7];
  const float* b_U    = (const float*)d_in[8];
  const float* W_V    = (const float*)d_in[9];
  const float* b_V    = (const float*)d_in[10];
  const float* W_Z    = (const float*)d_in[11];
  const float* b_Z    = (const float*)d_in[12];
  const float* os_g   = (const float*)d_in[13];
  const float* os_b   = (const float*)d_in[14];
  const float* embH   = (const float*)d_in[15];
  const float* W_out  = (const float*)d_in[16];
  const float* b_out  = (const float*)d_in[17];
  const float* W_gate = (const float*)d_in[18];
  const float* b_gate = (const float*)d_in[19];
  float* out = (float*)d_out;

  char* w = (char*)d_ws;
  float* Ub  = (float*)w;                w += (size_t)8184*512*4;          // U, then U*V_
  short* Zb  = (short*)w;                w += (size_t)16512*128*2;         // bf16 Z row-major
  short* VtF = (short*)w;                w += (size_t)8*32*(2*NT_)*64*8*2; // V B-frags
  short* ZkF = (short*)w;                w += (size_t)NB_*KT16_*4*64*8*2;  // Z-key A-frags
  short* xb  = (short*)w;                w += (size_t)16384*256*2;
  u64*  maskb = (u64*)w;                 w += (size_t)NB_*S0_*NT_*8;
  short* WpI = (short*)w;                w += (size_t)65536*2;
  short* WpU = (short*)w;                w += (size_t)131072*2;
  short* WpV = (short*)w;                w += (size_t)131072*2;
  short* WpZ = (short*)w;                w += (size_t)32768*2;
  short* WpO = (short*)w;                w += (size_t)131072*2;
  short* WpG = (short*)w;                w += (size_t)131072*2;

  hipLaunchKernelGGL(k_pack, dim3(32), dim3(256), 0, stream, W_init, WpI, 256, 256);
  hipLaunchKernelGGL(k_pack, dim3(64), dim3(256), 0, stream, W_U,   WpU, 256, 512);
  hipLaunchKernelGGL(k_pack, dim3(64), dim3(256), 0, stream, W_V,   WpV, 256, 512);
  hipLaunchKernelGGL(k_pack, dim3(16), dim3(256), 0, stream, W_Z,   WpZ, 256, 128);
  hipLaunchKernelGGL(k_pack, dim3(64), dim3(256), 0, stream, W_out, WpO, 512, 256);
  hipLaunchKernelGGL(k_pack, dim3(64), dim3(256), 0, stream, W_gate,WpG, 512, 256);
  hipLaunchKernelGGL(k_maskpack, dim3((NB_*S0_*NT_ + 3)/4), dim3(256), 0, stream, amask, maskb);

  hipLaunchKernelGGL(k_x, dim3(256), dim3(256), 0, stream,
      seq, WpI, b_init, ln_g, ln_b, xb);

  hipLaunchKernelGGL(k_gemm, dim3(128, 8), dim3(256), 0, stream,
      xb, WpU, b_U, Ub, 8184, 1023, 0, 512);
  hipLaunchKernelGGL(k_gemmZ, dim3(256, 2), dim3(256), 0, stream,
      xb, WpZ, b_Z, Zb);
  hipLaunchKernelGGL(k_packZ, dim3((NB_*KT16_*4 + 3)/4), dim3(256), 0, stream, Zb, ZkF);
  hipLaunchKernelGGL(k_gemmV, dim3(17, 8, 8), dim3(256), 0, stream,
      xb, WpV, b_V, VtF);

  hipLaunchKernelGGL(k_flash, dim3(512), dim3(256), 0, stream,
      Zb, ZkF, VtF, maskb, Ub, heights, os_g, os_b, embH);

  hipLaunchKernelGGL(k_outg, dim3(128), dim3(256), 0, stream,
      Ub, seq, WpO, b_out, WpG, b_gate, out);

  hipLaunchKernelGGL(k_copy, dim3(512), dim3(256), 0, stream, seq, out);
}

// Round 5
// 180.959 us; speedup vs baseline: 5.2060x; 1.2956x over previous
//
#include <hip/hip_runtime.h>
#include <cstdint>
#include <cstddef>

#define S_TOT 2048
#define S0_   1023
#define S1_   1025
#define D_    256
#define D2_   512
#define DZ_   128
#define NB_   8
#define NT_   17            // 17 * 64 padded keys = 1088
#define KT16_ 68            // 17*4 16-key groups
#define SCALE_INV (1.0f/16.0f)
#define XPAD  264           // 256 + 8 bf16 pad
#define UPAD  520           // 512 + 8 bf16 pad

typedef __attribute__((ext_vector_type(8))) short short8v;
typedef __attribute__((ext_vector_type(4))) short short4v;
typedef __attribute__((ext_vector_type(4))) float f32x4;
typedef unsigned long long u64;

__device__ __forceinline__ short f2bf(float f){
  unsigned u = __float_as_uint(f);
  unsigned r = (u + 0x7FFFu + ((u >> 16) & 1u)) >> 16;
  return (short)r;
}
__device__ __forceinline__ float bf2f(short s){
  return __uint_as_float(((unsigned)(unsigned short)s) << 16);
}
__device__ __forceinline__ float silu_f(float x){ return x / (1.f + __expf(-x)); }

// A/B fragment load from a row-major row (verified layout, round 1):
// elems 0..3: k = kt*32 + khi + j ; elems 4..7: +16
__device__ __forceinline__ short8v load_afrag(const short* arow, int kt, int khi){
  short4v lo = *reinterpret_cast<const short4v*>(arow + kt*32 + khi);
  short4v hi = *reinterpret_cast<const short4v*>(arow + kt*32 + khi + 16);
  short8v r = {lo[0],lo[1],lo[2],lo[3],hi[0],hi[1],hi[2],hi[3]};
  return r;
}

// ---------------- weight pack: fp32 (K,N) -> bf16 MFMA-B-fragment order -----
__global__ __launch_bounds__(256) void k_pack(const float* __restrict__ W,
                                              short* __restrict__ dst,
                                              int K, int N){
  const int wv = threadIdx.x >> 6, lane = threadIdx.x & 63;
  const int KT = K >> 5, NT = N >> 4;
  const int tile = blockIdx.x*4 + wv;
  if (tile >= KT*NT) return;
  const int nt = tile / KT, kt = tile - nt*KT;
  const int n = nt*16 + (lane & 15);
  const int kbase = kt*32 + ((lane>>4)<<2);
  short8v v;
  #pragma unroll
  for (int j=0;j<8;++j){
    int k = kbase + (j&3) + ((j>>2)<<4);
    v[j] = f2bf(W[(size_t)k*N + n]);
  }
  *reinterpret_cast<short8v*>(dst + ((size_t)tile*64 + lane)*8) = v;
}

// ---------------- mask pack: bool bytes -> u64 bitmask per 64-key tile ------
__global__ __launch_bounds__(256) void k_maskpack(const unsigned char* __restrict__ amask,
                                                  u64* __restrict__ maskb){
  const int lane = threadIdx.x & 63;
  const int w = blockIdx.x*4 + (threadIdx.x >> 6);
  if (w >= NB_*S0_*NT_) return;
  int b = w / (S0_*NT_);
  int rem = w - b*(S0_*NT_);
  int q = rem / NT_;
  int t = rem - q*NT_;
  int key = t*64 + lane;
  unsigned char v = 0;
  if (key < S1_) v = amask[((size_t)(b*S_TOT + q))*S_TOT + S0_ + key];
  u64 bits = __ballot(v != 0);
  if (lane == 0) maskb[w] = bits;
}

// ---------------- kernel 1a: x = LN(seq@W_init + b) -> bf16 -----------------
__global__ __launch_bounds__(256) void k_x(
    const float* __restrict__ seq, const short* __restrict__ Wp,
    const float* __restrict__ b_init,
    const float* __restrict__ ln_g, const float* __restrict__ ln_b,
    short* __restrict__ xb)
{
  __shared__ short s_a[64*XPAD];
  const int tid = threadIdx.x, lane = tid & 63, wv = tid >> 6;
  const int R0 = blockIdx.x * 64;
  const int colb = lane & 15, khi = (lane>>4)<<2;

  for (int c = tid; c < 64*64; c += 256){
    int row = c >> 6, c4 = (c & 63) << 2;
    float4 f = *reinterpret_cast<const float4*>(seq + (size_t)(R0+row)*D_ + c4);
    short4v h = { f2bf(f.x), f2bf(f.y), f2bf(f.z), f2bf(f.w) };
    *reinterpret_cast<short4v*>(&s_a[row*XPAD + c4]) = h;
  }
  __syncthreads();

  f32x4 acc[16];
  #pragma unroll
  for (int nt=0;nt<16;++nt) acc[nt] = (f32x4){0.f,0.f,0.f,0.f};

  const short* arow = &s_a[(wv*16 + colb)*XPAD];
  #pragma unroll
  for (int kt=0; kt<8; ++kt){
    short8v a = load_afrag(arow, kt, khi);
    #pragma unroll
    for (int nt=0; nt<16; ++nt){
      short8v b = *reinterpret_cast<const short8v*>(Wp + ((size_t)(nt*8 + kt)*64 + lane)*8);
      acc[nt] = __builtin_amdgcn_mfma_f32_16x16x32_bf16(a, b, acc[nt], 0, 0, 0);
    }
  }

  float sum[4] = {0.f,0.f,0.f,0.f};
  #pragma unroll
  for (int nt=0; nt<16; ++nt){
    float bv = b_init[nt*16 + colb];
    #pragma unroll
    for (int r=0;r<4;++r){ acc[nt][r] += bv; sum[r] += acc[nt][r]; }
  }
  #pragma unroll
  for (int r=0;r<4;++r){
    #pragma unroll
    for (int m=1;m<16;m<<=1) sum[r] += __shfl_xor(sum[r], m, 64);
    sum[r] *= (1.f/256.f);
  }
  float var[4] = {0.f,0.f,0.f,0.f};
  #pragma unroll
  for (int nt=0; nt<16; ++nt)
    #pragma unroll
    for (int r=0;r<4;++r){ float d = acc[nt][r]-sum[r]; var[r] += d*d; }
  #pragma unroll
  for (int r=0;r<4;++r){
    #pragma unroll
    for (int m=1;m<16;m<<=1) var[r] += __shfl_xor(var[r], m, 64);
    var[r] = rsqrtf(var[r]*(1.f/256.f) + 1e-5f);
  }
  #pragma unroll
  for (int nt=0; nt<16; ++nt){
    int col = nt*16 + colb;
    float g = ln_g[col], bb = ln_b[col];
    #pragma unroll
    for (int r=0;r<4;++r){
      float xn = (acc[nt][r]-sum[r])*var[r]*g + bb;
      s_a[(wv*16 + ((lane>>4)<<2) + r)*XPAD + col] = f2bf(xn);
    }
  }
  __syncthreads();
  for (int c = tid; c < 64*32; c += 256){
    int row = c >> 5, c8 = (c & 31) << 3;
    *reinterpret_cast<short8v*>(xb + (size_t)(R0+row)*D_ + c8) =
        *reinterpret_cast<const short8v*>(&s_a[row*XPAD + c8]);
  }
}

// ---------------- kernel 1b: U = silu(x@W+b), fp32 out ---------------------
__global__ __launch_bounds__(256) void k_gemm(
    const short* __restrict__ xb, const short* __restrict__ Wp,
    const float* __restrict__ bias, float* __restrict__ outp,
    int M, int RPB, int OFF, int Nld)
{
  __shared__ short s_a[64*XPAD];
  const int tid = threadIdx.x, lane = tid & 63, wv = tid >> 6;
  const int wy = wv >> 1, wx = wv & 1;
  const int R0 = blockIdx.x * 64;
  const int C0 = blockIdx.y * 64;
  const int colb = lane & 15, khi = (lane>>4)<<2;

  for (int c = tid; c < 64*32; c += 256){
    int r = c >> 5, c8 = (c & 31) << 3;
    int orow = R0 + r; if (orow > M-1) orow = M-1;
    int bb = orow / RPB; int s = orow - bb*RPB;
    size_t xrow = (size_t)bb*S_TOT + s + OFF;
    *reinterpret_cast<short8v*>(&s_a[r*XPAD + c8]) =
        *reinterpret_cast<const short8v*>(xb + xrow*D_ + c8);
  }
  __syncthreads();

  f32x4 acc[2][2];
  #pragma unroll
  for(int i=0;i<2;++i)
    #pragma unroll
    for(int j=0;j<2;++j) acc[i][j] = (f32x4){0.f,0.f,0.f,0.f};

  const short* ar0 = &s_a[(wy*32 + colb)*XPAD];
  const short* ar1 = ar0 + 16*XPAD;
  const int ntg = (C0 >> 4) + wx*2;
  #pragma unroll
  for (int kt=0; kt<8; ++kt){
    short8v a0 = load_afrag(ar0, kt, khi);
    short8v a1 = load_afrag(ar1, kt, khi);
    short8v b0 = *reinterpret_cast<const short8v*>(Wp + ((size_t)((ntg+0)*8 + kt)*64 + lane)*8);
    short8v b1 = *reinterpret_cast<const short8v*>(Wp + ((size_t)((ntg+1)*8 + kt)*64 + lane)*8);
    acc[0][0] = __builtin_amdgcn_mfma_f32_16x16x32_bf16(a0, b0, acc[0][0], 0,0,0);
    acc[0][1] = __builtin_amdgcn_mfma_f32_16x16x32_bf16(a0, b1, acc[0][1], 0,0,0);
    acc[1][0] = __builtin_amdgcn_mfma_f32_16x16x32_bf16(a1, b0, acc[1][0], 0,0,0);
    acc[1][1] = __builtin_amdgcn_mfma_f32_16x16x32_bf16(a1, b1, acc[1][1], 0,0,0);
  }
  #pragma unroll
  for (int sj=0; sj<2; ++sj){
    int col = C0 + wx*32 + sj*16 + colb;
    float bv = bias[col];
    #pragma unroll
    for (int si=0; si<2; ++si){
      #pragma unroll
      for (int r=0;r<4;++r){
        int orow = R0 + wy*32 + si*16 + ((lane>>4)<<2) + r;
        if (orow < M) outp[(size_t)orow*Nld + col] = silu_f(acc[si][sj][r] + bv);
      }
    }
  }
}

// ---------------- kernel 1c: Z = silu(x@W_Z+b) -> bf16 row-major ------------
__global__ __launch_bounds__(256) void k_gemmZ(
    const short* __restrict__ xb, const short* __restrict__ Wp,
    const float* __restrict__ bias, short* __restrict__ Zb)
{
  __shared__ short s_a[64*XPAD];
  const int tid = threadIdx.x, lane = tid & 63, wv = tid >> 6;
  const int wy = wv >> 1, wx = wv & 1;
  const int R0 = blockIdx.x * 64;
  const int C0 = blockIdx.y * 64;
  const int colb = lane & 15, khi = (lane>>4)<<2;

  for (int c = tid; c < 64*32; c += 256){
    int r = c >> 5, c8 = (c & 31) << 3;
    size_t xrow = (size_t)(R0 + r);
    *reinterpret_cast<short8v*>(&s_a[r*XPAD + c8]) =
        *reinterpret_cast<const short8v*>(xb + xrow*D_ + c8);
  }
  __syncthreads();

  f32x4 acc[2][2];
  #pragma unroll
  for(int i=0;i<2;++i)
    #pragma unroll
    for(int j=0;j<2;++j) acc[i][j] = (f32x4){0.f,0.f,0.f,0.f};

  const short* ar0 = &s_a[(wy*32 + colb)*XPAD];
  const short* ar1 = ar0 + 16*XPAD;
  const int ntg = (C0 >> 4) + wx*2;
  #pragma unroll
  for (int kt=0; kt<8; ++kt){
    short8v a0 = load_afrag(ar0, kt, khi);
    short8v a1 = load_afrag(ar1, kt, khi);
    short8v b0 = *reinterpret_cast<const short8v*>(Wp + ((size_t)((ntg+0)*8 + kt)*64 + lane)*8);
    short8v b1 = *reinterpret_cast<const short8v*>(Wp + ((size_t)((ntg+1)*8 + kt)*64 + lane)*8);
    acc[0][0] = __builtin_amdgcn_mfma_f32_16x16x32_bf16(a0, b0, acc[0][0], 0,0,0);
    acc[0][1] = __builtin_amdgcn_mfma_f32_16x16x32_bf16(a0, b1, acc[0][1], 0,0,0);
    acc[1][0] = __builtin_amdgcn_mfma_f32_16x16x32_bf16(a1, b0, acc[1][0], 0,0,0);
    acc[1][1] = __builtin_amdgcn_mfma_f32_16x16x32_bf16(a1, b1, acc[1][1], 0,0,0);
  }
  #pragma unroll
  for (int sj=0; sj<2; ++sj){
    int col = C0 + wx*32 + sj*16 + colb;
    float bv = bias[col];
    #pragma unroll
    for (int si=0; si<2; ++si){
      #pragma unroll
      for (int r=0;r<4;++r){
        int orow = R0 + wy*32 + si*16 + ((lane>>4)<<2) + r;
        Zb[(size_t)orow*DZ_ + col] = f2bf(silu_f(acc[si][sj][r] + bv));
      }
    }
  }
}

// ------- kernel 1c2: pack Z key rows -> A-fragment order (for flash QK) -----
__global__ __launch_bounds__(256) void k_packZ(const short* __restrict__ Zb,
                                               short* __restrict__ ZkF){
  const int lane = threadIdx.x & 63;
  const int w = blockIdx.x*4 + (threadIdx.x >> 6);
  if (w >= NB_*KT16_*4) return;
  const int b = w / (KT16_*4);
  const int rem = w - b*(KT16_*4);
  const int kt16 = rem >> 2, kt = rem & 3;
  int key = kt16*16 + (lane & 15); if (key > 1024) key = 1024;
  const short* zr = Zb + ((size_t)(b*S_TOT + S0_ + key))*DZ_ + kt*32 + ((lane>>4)<<2);
  short4v lo = *reinterpret_cast<const short4v*>(zr);
  short4v hi = *reinterpret_cast<const short4v*>(zr + 16);
  short8v f = {lo[0],lo[1],lo[2],lo[3],hi[0],hi[1],hi[2],hi[3]};
  *reinterpret_cast<short8v*>(ZkF + ((size_t)w*64 + lane)*8) = f;
}

// ---------------- kernel 1d: V -> bf16 B-fragment order VtF -----------------
__global__ __launch_bounds__(256) void k_gemmV(
    const short* __restrict__ xb, const short* __restrict__ Wp,
    const float* __restrict__ bias, short* __restrict__ VtF)
{
  __shared__ short s_a[64*XPAD];
  __shared__ short s_t[64][72];
  const int tid = threadIdx.x, lane = tid & 63, wv = tid >> 6;
  const int wy = wv >> 1, wx = wv & 1;
  const int R0 = blockIdx.x * 64;     // key base within batch (tile t = R0/64)
  const int C0 = blockIdx.y * 64;     // v base
  const int b  = blockIdx.z;
  const int colb = lane & 15, khi = (lane>>4)<<2;

  for (int c = tid; c < 64*32; c += 256){
    int r = c >> 5, c8 = (c & 31) << 3;
    int k = R0 + r; if (k > 1024) k = 1024;
    size_t xrow = (size_t)b*S_TOT + S0_ + k;
    *reinterpret_cast<short8v*>(&s_a[r*XPAD + c8]) =
        *reinterpret_cast<const short8v*>(xb + xrow*D_ + c8);
  }
  __syncthreads();

  f32x4 acc[2][2];
  #pragma unroll
  for(int i=0;i<2;++i)
    #pragma unroll
    for(int j=0;j<2;++j) acc[i][j] = (f32x4){0.f,0.f,0.f,0.f};

  const short* ar0 = &s_a[(wy*32 + colb)*XPAD];
  const short* ar1 = ar0 + 16*XPAD;
  const int ntg = (C0 >> 4) + wx*2;
  #pragma unroll
  for (int kt=0; kt<8; ++kt){
    short8v a0 = load_afrag(ar0, kt, khi);
    short8v a1 = load_afrag(ar1, kt, khi);
    short8v b0 = *reinterpret_cast<const short8v*>(Wp + ((size_t)((ntg+0)*8 + kt)*64 + lane)*8);
    short8v b1 = *reinterpret_cast<const short8v*>(Wp + ((size_t)((ntg+1)*8 + kt)*64 + lane)*8);
    acc[0][0] = __builtin_amdgcn_mfma_f32_16x16x32_bf16(a0, b0, acc[0][0], 0,0,0);
    acc[0][1] = __builtin_amdgcn_mfma_f32_16x16x32_bf16(a0, b1, acc[0][1], 0,0,0);
    acc[1][0] = __builtin_amdgcn_mfma_f32_16x16x32_bf16(a1, b0, acc[1][0], 0,0,0);
    acc[1][1] = __builtin_amdgcn_mfma_f32_16x16x32_bf16(a1, b1, acc[1][1], 0,0,0);
  }
  // silu + transpose into LDS [v_local][key_local]
  #pragma unroll
  for (int sj=0; sj<2; ++sj){
    int cl = wx*32 + sj*16 + colb;
    float bv = bias[C0 + cl];
    #pragma unroll
    for (int si=0; si<2; ++si){
      #pragma unroll
      for (int r=0;r<4;++r){
        int rl = wy*32 + si*16 + ((lane>>4)<<2) + r;
        s_t[cl][rl] = f2bf(silu_f(acc[si][sj][r] + bv));
      }
    }
  }
  __syncthreads();
  // emit B-fragments (zero pad for key >= S1_)
  {
    const int vt_l = tid >> 6;           // 0..3: v-tile within C0
    const int vloc = vt_l*16 + (lane & 15);
    const int krow = (lane>>4)<<2;
    const int t = R0 >> 6;
    #pragma unroll
    for (int kt=0; kt<2; ++kt){
      short8v f;
      #pragma unroll
      for (int j=0;j<8;++j){
        int kl = kt*32 + krow + (j&3) + ((j>>2)<<4);
        short v = s_t[vloc][kl];
        if (R0 + kl >= S1_) v = 0;
        f[j] = v;
      }
      size_t o = (((size_t)b*32 + (C0>>4) + vt_l)*(2*NT_) + 2*t + kt)*64 + lane;
      *reinterpret_cast<short8v*>(VtF + o*8) = f;
    }
  }
}

// ---------------- kernel 2: flash attention, 4 cooperating waves ------------
__global__ __launch_bounds__(256,2) void k_flash(
    const short* __restrict__ Zb, const short* __restrict__ ZkF,
    const short* __restrict__ VtF, const u64* __restrict__ maskb,
    float* __restrict__ Ub, const int* __restrict__ heights,
    const float* __restrict__ os_g, const float* __restrict__ os_b,
    const float* __restrict__ embH)
{
  __shared__ short  s_qg[16][132];
  __shared__ float  s_qh[16][12];
  __shared__ float  s_qb[16];
  __shared__ int    s_hk[NT_*64];
  __shared__ u64    s_mb[16][NT_];
  __shared__ float  s_mx[2][4][16];
  __shared__ float  s_sm[2][4][16];
  __shared__ short8v s_pl[8][64];   // [buf*4 + tile][lane]
  __shared__ short8v s_ph[8][64];

  const int tid = threadIdx.x, lane = tid & 63, wv = tid >> 6;
  const int b  = blockIdx.x & 7;
  const int qt = blockIdx.x >> 3;
  const int q0 = qt * 16;

  // ---- Q prep: 16 threads per q-row, 8 dz each
  {
    int row = tid >> 4, part = tid & 15;
    int q = q0 + row; if (q > S0_-1) q = S0_-1;
    const short* zrow = Zb + ((size_t)(b*S_TOT + q))*DZ_ + part*8;
    float qb_acc = 0.f;
    float qh_acc[10];
    #pragma unroll
    for (int h=0;h<10;++h) qh_acc[h] = 0.f;
    #pragma unroll
    for (int e=0; e<8; ++e){
      int dz = part*8 + e;
      float z = bf2f(zrow[e]);
      float Q  = z*os_g[dz]      + os_b[dz];
      float Qp = z*os_g[DZ_+dz]  + os_b[DZ_+dz];
      s_qg[row][dz] = f2bf(Q * os_g[2*DZ_+dz]);
      qb_acc += Q * os_b[2*DZ_+dz];
      #pragma unroll
      for (int h=0;h<10;++h) qh_acc[h] += Qp * embH[h*DZ_ + dz];
    }
    #pragma unroll
    for (int m=1;m<16;m<<=1){
      qb_acc += __shfl_xor(qb_acc, m, 64);
      #pragma unroll
      for (int h=0;h<10;++h) qh_acc[h] += __shfl_xor(qh_acc[h], m, 64);
    }
    if (part == 0){
      s_qb[row] = qb_acc;
      #pragma unroll
      for (int h=0;h<10;++h) s_qh[row][h] = qh_acc[h];
    }
  }
  for (int k = tid; k < NT_*64; k += 256)
    s_hk[k] = (k < S1_) ? heights[b*S_TOT + S0_ + k] : 0;
  for (int idx = tid; idx < 16*NT_; idx += 256){
    int qq = idx / NT_, tt = idx - qq*NT_;
    int qr = q0 + qq; if (qr > S0_-1) qr = S0_-1;
    s_mb[qq][tt] = maskb[((size_t)(b*S0_ + qr))*NT_ + tt];
  }
  __syncthreads();

  const int qcol = lane & 15, khi = (lane>>4)<<2;
  int qme = q0 + qcol; if (qme > S0_-1) qme = S0_-1;
  const int hq = heights[b*S_TOT + qme];
  const float qb = s_qb[qcol];

  short8v qgf[4];
  #pragma unroll
  for (int kt=0; kt<4; ++kt) qgf[kt] = load_afrag(&s_qg[qcol][0], kt, khi);

  float mcol = -1e30f;
  float mrow[4] = {-1e30f,-1e30f,-1e30f,-1e30f};
  float lrow[4] = {0.f,0.f,0.f,0.f};
  f32x4 O[8];
  #pragma unroll
  for (int vt=0; vt<8; ++vt) O[vt] = (f32x4){0.f,0.f,0.f,0.f};

  int buf = 0;
  for (int it=0; it<5; ++it){
    const int t = it*4 + wv;
    const bool tvalid = (t < NT_);
    f32x4 sc[4];
    float tm = -1e30f;
    // ---- phase A: own tile's QK^T + bias + mask
    if (tvalid){
      #pragma unroll
      for (int st=0; st<4; ++st){
        f32x4 c = (f32x4){0.f,0.f,0.f,0.f};
        #pragma unroll
        for (int kt=0; kt<4; ++kt){
          short8v a = *reinterpret_cast<const short8v*>(
              ZkF + (((size_t)(b*KT16_ + t*4 + st)*4 + kt)*64 + lane)*8);
          c = __builtin_amdgcn_mfma_f32_16x16x32_bf16(a, qgf[kt], c, 0,0,0);
        }
        sc[st] = c;
      }
      u64 mb = s_mb[qcol][t];
      #pragma unroll
      for (int st=0; st<4; ++st){
        int4 hk4 = *reinterpret_cast<const int4*>(&s_hk[t*64 + st*16 + khi]);
        #pragma unroll
        for (int r=0;r<4;++r){
          int hk = (&hk4.x)[r];
          int idx = min(max(hk - hq, 1), 10) - 1;
          float v = (sc[st][r] + qb + s_qh[qcol][idx]) * SCALE_INV;
          int kl = st*16 + khi + r;
          v = ((mb >> kl) & 1ull) ? v : -9999.f;
          sc[st][r] = v;
          tm = fmaxf(tm, v);
        }
      }
      tm = fmaxf(tm, __shfl_xor(tm, 16, 64));
      tm = fmaxf(tm, __shfl_xor(tm, 32, 64));
    }
    if (lane < 16) s_mx[buf][wv][lane] = tm;
    __syncthreads();

    // ---- phase B: combined max, defer-max rescale, exp, pack P
    float cmc = fmaxf(fmaxf(s_mx[buf][0][qcol], s_mx[buf][1][qcol]),
                      fmaxf(s_mx[buf][2][qcol], s_mx[buf][3][qcol]));
    if (__any(cmc > mcol + 8.f)){
      mcol = fmaxf(mcol, cmc);
      #pragma unroll
      for (int r=0;r<4;++r){
        int qr = khi + r;
        float cmr = fmaxf(fmaxf(s_mx[buf][0][qr], s_mx[buf][1][qr]),
                          fmaxf(s_mx[buf][2][qr], s_mx[buf][3][qr]));
        float mn = fmaxf(mrow[r], cmr);
        float s = __expf(mrow[r] - mn);
        lrow[r] *= s; mrow[r] = mn;
        #pragma unroll
        for (int vt=0; vt<8; ++vt) O[vt][r] *= s;
      }
    }
    float ls = 0.f;
    if (tvalid){
      #pragma unroll
      for (int st=0; st<4; ++st)
        #pragma unroll
        for (int r=0;r<4;++r){
          float p = __expf(sc[st][r] - mcol);
          ls += p; sc[st][r] = p;
        }
    }
    ls += __shfl_xor(ls, 16, 64);
    ls += __shfl_xor(ls, 32, 64);
    if (lane < 16) s_sm[buf][wv][lane] = ls;
    if (tvalid){
      short8v pa0, pa1;
      #pragma unroll
      for (int j=0;j<8;++j){
        pa0[j] = f2bf(sc[(j>>2)][j&3]);
        pa1[j] = f2bf(sc[2 + (j>>2)][j&3]);
      }
      s_pl[buf*4 + wv][lane] = pa0;
      s_ph[buf*4 + wv][lane] = pa1;
    }
    __syncthreads();

    // ---- phase C: accumulate l; PV over the 4 tiles for own v-slice
    #pragma unroll
    for (int r=0;r<4;++r){
      int qr = khi + r;
      lrow[r] += s_sm[buf][0][qr] + s_sm[buf][1][qr] + s_sm[buf][2][qr] + s_sm[buf][3][qr];
    }
    #pragma unroll
    for (int tw=0; tw<4; ++tw){
      int tl = it*4 + tw;
      if (tl >= NT_) break;
      short8v pa0 = s_pl[buf*4 + tw][lane];
      short8v pa1 = s_ph[buf*4 + tw][lane];
      #pragma unroll
      for (int vt=0; vt<8; ++vt){
        size_t vb = ((size_t)b*32 + wv*8 + vt)*(2*NT_) + 2*tl;
        short8v b0 = *reinterpret_cast<const short8v*>(VtF + (vb*64 + lane)*8);
        short8v b1 = *reinterpret_cast<const short8v*>(VtF + ((vb+1)*64 + lane)*8);
        O[vt] = __builtin_amdgcn_mfma_f32_16x16x32_bf16(pa0, b0, O[vt], 0,0,0);
        O[vt] = __builtin_amdgcn_mfma_f32_16x16x32_bf16(pa1, b1, O[vt], 0,0,0);
      }
    }
    buf ^= 1;
  }

  // ---- epilogue: U *= O / l
  #pragma unroll
  for (int r=0;r<4;++r){
    int q = q0 + khi + r;
    if (q < S0_){
      float inv = 1.f / lrow[r];
      #pragma unroll
      for (int vt=0; vt<8; ++vt){
        size_t off = ((size_t)(b*S0_ + q))*D2_ + wv*128 + vt*16 + qcol;
        Ub[off] = Ub[off] * O[vt][r] * inv;
      }
    }
  }
}

// ---------------- kernel 3: fused out-proj + gating, 16 rows/block ----------
// 4 waves; wave wv owns n-tiles wv*4..wv*4+3. Grid = 512 blocks.
__global__ __launch_bounds__(256) void k_outg(
    const float* __restrict__ UV, const float* __restrict__ seq,
    const short* __restrict__ Wpo, const float* __restrict__ b_out,
    const short* __restrict__ Wpg, const float* __restrict__ b_gate,
    float* __restrict__ out)
{
  __shared__ short sUV[16*UPAD];   // 16 rows x 512 (bf16)
  __shared__ short sO [16*XPAD];   // o (bf16)
  __shared__ short sR [16*XPAD];   // res (bf16)
  const int tid = threadIdx.x, lane = tid & 63, wv = tid >> 6;
  const int R0 = blockIdx.x * 16;
  const int colb = lane & 15, khi = (lane>>4)<<2;

  // stage UV (16x512) and res (16x256) as bf16
  for (int c = tid; c < 16*128; c += 256){
    int r = c >> 7, c4 = (c & 127) << 2;
    int orow = min(R0 + r, 8183);
    float4 f = *reinterpret_cast<const float4*>(UV + (size_t)orow*D2_ + c4);
    short4v h = { f2bf(f.x), f2bf(f.y), f2bf(f.z), f2bf(f.w) };
    *reinterpret_cast<short4v*>(&sUV[r*UPAD + c4]) = h;
  }
  for (int c = tid; c < 16*64; c += 256){
    int r = c >> 6, c4 = (c & 63) << 2;
    int orow = min(R0 + r, 8183);
    int bb = orow / S0_; int s = orow - bb*S0_;
    float4 f = *reinterpret_cast<const float4*>(seq + ((size_t)bb*S_TOT + s)*D_ + c4);
    short4v h = { f2bf(f.x), f2bf(f.y), f2bf(f.z), f2bf(f.w) };
    *reinterpret_cast<short4v*>(&sR[r*XPAD + c4]) = h;
  }
  __syncthreads();

  // phase 1: o = UV @ W_out + b  (each wave: 4 n-tiles, K=512)
  f32x4 acc_o[4];
  #pragma unroll
  for (int j=0;j<4;++j) acc_o[j] = (f32x4){0.f,0.f,0.f,0.f};
  const short* arow = &sUV[colb*UPAD];
  #pragma unroll
  for (int kt=0; kt<16; ++kt){
    short8v a = load_afrag(arow, kt, khi);
    #pragma unroll
    for (int j=0;j<4;++j){
      int nt = wv*4 + j;
      short8v b = *reinterpret_cast<const short8v*>(Wpo + ((size_t)(nt*16 + kt)*64 + lane)*8);
      acc_o[j] = __builtin_amdgcn_mfma_f32_16x16x32_bf16(a, b, acc_o[j], 0,0,0);
    }
  }
  #pragma unroll
  for (int j=0;j<4;++j){
    int col = (wv*4+j)*16 + colb;
    float bv = b_out[col];
    #pragma unroll
    for (int r=0;r<4;++r){
      acc_o[j][r] += bv;
      sO[(khi + r)*XPAD + col] = f2bf(acc_o[j][r]);
    }
  }
  __syncthreads();

  // phase 2: gate = sigmoid([o, res] @ W_gate + b)
  f32x4 acc_g[4];
  #pragma unroll
  for (int j=0;j<4;++j) acc_g[j] = (f32x4){0.f,0.f,0.f,0.f};
  const short* orow_p = &sO[colb*XPAD];
  const short* rrow_p = &sR[colb*XPAD];
  #pragma unroll
  for (int kt=0; kt<8; ++kt){
    short8v a = load_afrag(orow_p, kt, khi);
    #pragma unroll
    for (int j=0;j<4;++j){
      int nt = wv*4 + j;
      short8v b = *reinterpret_cast<const short8v*>(Wpg + ((size_t)(nt*16 + kt)*64 + lane)*8);
      acc_g[j] = __builtin_amdgcn_mfma_f32_16x16x32_bf16(a, b, acc_g[j], 0,0,0);
    }
  }
  #pragma unroll
  for (int kt=0; kt<8; ++kt){
    short8v a = load_afrag(rrow_p, kt, khi);
    #pragma unroll
    for (int j=0;j<4;++j){
      int nt = wv*4 + j;
      short8v b = *reinterpret_cast<const short8v*>(Wpg + ((size_t)(nt*16 + 8 + kt)*64 + lane)*8);
      acc_g[j] = __builtin_amdgcn_mfma_f32_16x16x32_bf16(a, b, acc_g[j], 0,0,0);
    }
  }

  // final: sigmoid gate + mix (res re-read fp32 from global for accuracy)
  #pragma unroll
  for (int j=0;j<4;++j){
    int col = (wv*4+j)*16 + colb;
    float bg = b_gate[col];
    #pragma unroll
    for (int r=0;r<4;++r){
      int orow = R0 + khi + r;
      if (orow < 8184){
        int bb = orow / S0_; int s = orow - bb*S0_;
        float res = seq[((size_t)bb*S_TOT + s)*D_ + col];
        float g = 1.f/(1.f + __expf(-(acc_g[j][r] + bg)));
        out[((size_t)bb*S_TOT + s)*D_ + col] = g*acc_o[j][r] + (1.f-g)*res;
      }
    }
  }
}

// ---------------- kernel 4: passthrough tail rows ---------------------------
__global__ void k_copy(const float* __restrict__ seq, float* __restrict__ out){
  const int per_b = S1_ * (D_/4);
  const int total = NB_ * per_b;
  for (int i = blockIdx.x*blockDim.x + threadIdx.x; i < total; i += gridDim.x*blockDim.x) {
    int b = i / per_b;
    int off = i - b*per_b;
    size_t base = ((size_t)b*S_TOT + S0_) * (size_t)(D_/4);
    reinterpret_cast<float4*>(out)[base + off] =
        reinterpret_cast<const float4*>(seq)[base + off];
  }
}

extern "C" void kernel_launch(void* const* d_in, const int* in_sizes, int n_in,
                              void* d_out, int out_size, void* d_ws, size_t ws_size,
                              hipStream_t stream)
{
  const float* seq    = (const float*)d_in[0];
  const unsigned char* amask = (const unsigned char*)d_in[1];
  const int*   heights= (const int*)d_in[2];
  const float* W_init = (const float*)d_in[3];
  const float* b_init = (const float*)d_in[4];
  const float* ln_g   = (const float*)d_in[5];
  const float* ln_b   = (const float*)d_in[6];
  const float* W_U    = (const float*)d_in[7];
  const float* b_U    = (const float*)d_in[8];
  const float* W_V    = (const float*)d_in[9];
  const float* b_V    = (const float*)d_in[10];
  const float* W_Z    = (const float*)d_in[11];
  const float* b_Z    = (const float*)d_in[12];
  const float* os_g   = (const float*)d_in[13];
  const float* os_b   = (const float*)d_in[14];
  const float* embH   = (const float*)d_in[15];
  const float* W_out  = (const float*)d_in[16];
  const float* b_out  = (const float*)d_in[17];
  const float* W_gate = (const float*)d_in[18];
  const float* b_gate = (const float*)d_in[19];
  float* out = (float*)d_out;

  char* w = (char*)d_ws;
  float* Ub  = (float*)w;                w += (size_t)8184*512*4;          // U, then U*V_
  short* Zb  = (short*)w;                w += (size_t)16512*128*2;         // bf16 Z row-major
  short* VtF = (short*)w;                w += (size_t)8*32*(2*NT_)*64*8*2; // V B-frags
  short* ZkF = (short*)w;                w += (size_t)NB_*KT16_*4*64*8*2;  // Z-key A-frags
  short* xb  = (short*)w;                w += (size_t)16384*256*2;
  u64*  maskb = (u64*)w;                 w += (size_t)NB_*S0_*NT_*8;
  short* WpI = (short*)w;                w += (size_t)65536*2;
  short* WpU = (short*)w;                w += (size_t)131072*2;
  short* WpV = (short*)w;                w += (size_t)131072*2;
  short* WpZ = (short*)w;                w += (size_t)32768*2;
  short* WpO = (short*)w;                w += (size_t)131072*2;
  short* WpG = (short*)w;                w += (size_t)131072*2;

  hipLaunchKernelGGL(k_pack, dim3(32), dim3(256), 0, stream, W_init, WpI, 256, 256);
  hipLaunchKernelGGL(k_pack, dim3(64), dim3(256), 0, stream, W_U,   WpU, 256, 512);
  hipLaunchKernelGGL(k_pack, dim3(64), dim3(256), 0, stream, W_V,   WpV, 256, 512);
  hipLaunchKernelGGL(k_pack, dim3(16), dim3(256), 0, stream, W_Z,   WpZ, 256, 128);
  hipLaunchKernelGGL(k_pack, dim3(64), dim3(256), 0, stream, W_out, WpO, 512, 256);
  hipLaunchKernelGGL(k_pack, dim3(64), dim3(256), 0, stream, W_gate,WpG, 512, 256);
  hipLaunchKernelGGL(k_maskpack, dim3((NB_*S0_*NT_ + 3)/4), dim3(256), 0, stream, amask, maskb);

  hipLaunchKernelGGL(k_x, dim3(256), dim3(256), 0, stream,
      seq, WpI, b_init, ln_g, ln_b, xb);

  hipLaunchKernelGGL(k_gemm, dim3(128, 8), dim3(256), 0, stream,
      xb, WpU, b_U, Ub, 8184, 1023, 0, 512);
  hipLaunchKernelGGL(k_gemmZ, dim3(256, 2), dim3(256), 0, stream,
      xb, WpZ, b_Z, Zb);
  hipLaunchKernelGGL(k_packZ, dim3((NB_*KT16_*4 + 3)/4), dim3(256), 0, stream, Zb, ZkF);
  hipLaunchKernelGGL(k_gemmV, dim3(17, 8, 8), dim3(256), 0, stream,
      xb, WpV, b_V, VtF);

  hipLaunchKernelGGL(k_flash, dim3(512), dim3(256), 0, stream,
      Zb, ZkF, VtF, maskb, Ub, heights, os_g, os_b, embH);

  hipLaunchKernelGGL(k_outg, dim3(512), dim3(256), 0, stream,
      Ub, seq, WpO, b_out, WpG, b_gate, out);

  hipLaunchKernelGGL(k_copy, dim3(512), dim3(256), 0, stream, seq, out);
}

// Round 6
// 143.560 us; speedup vs baseline: 6.5621x; 1.2605x over previous
//
#include <hip/hip_runtime.h>
#include <cstdint>
#include <cstddef>

#define S_TOT 2048
#define S0_   1023
#define S1_   1025
#define D_    256
#define D2_   512
#define DZ_   128
#define NB_   8
#define NT_   17            // 17 * 64 padded keys = 1088
#define KT16_ 68            // 17*4 16-key groups
#define SCALE_INV (1.0f/16.0f)
#define XPAD  264           // 256 + 8 bf16 pad
#define UPAD  520           // 512 + 8 bf16 pad

typedef __attribute__((ext_vector_type(8))) short short8v;
typedef __attribute__((ext_vector_type(4))) short short4v;
typedef __attribute__((ext_vector_type(4))) float f32x4;
typedef unsigned long long u64;

__device__ __forceinline__ short f2bf(float f){
  unsigned u = __float_as_uint(f);
  unsigned r = (u + 0x7FFFu + ((u >> 16) & 1u)) >> 16;
  return (short)r;
}
__device__ __forceinline__ float bf2f(short s){
  return __uint_as_float(((unsigned)(unsigned short)s) << 16);
}
__device__ __forceinline__ float silu_f(float x){ return x / (1.f + __expf(-x)); }

// A/B fragment load from a row-major row (verified layout, round 1):
// elems 0..3: k = kt*32 + khi + j ; elems 4..7: +16
__device__ __forceinline__ short8v load_afrag(const short* arow, int kt, int khi){
  short4v lo = *reinterpret_cast<const short4v*>(arow + kt*32 + khi);
  short4v hi = *reinterpret_cast<const short4v*>(arow + kt*32 + khi + 16);
  short8v r = {lo[0],lo[1],lo[2],lo[3],hi[0],hi[1],hi[2],hi[3]};
  return r;
}

// ---------------- weight pack: fp32 (K,N) -> bf16 MFMA-B-fragment order -----
__global__ __launch_bounds__(256) void k_pack(const float* __restrict__ W,
                                              short* __restrict__ dst,
                                              int K, int N){
  const int wv = threadIdx.x >> 6, lane = threadIdx.x & 63;
  const int KT = K >> 5, NT = N >> 4;
  const int tile = blockIdx.x*4 + wv;
  if (tile >= KT*NT) return;
  const int nt = tile / KT, kt = tile - nt*KT;
  const int n = nt*16 + (lane & 15);
  const int kbase = kt*32 + ((lane>>4)<<2);
  short8v v;
  #pragma unroll
  for (int j=0;j<8;++j){
    int k = kbase + (j&3) + ((j>>2)<<4);
    v[j] = f2bf(W[(size_t)k*N + n]);
  }
  *reinterpret_cast<short8v*>(dst + ((size_t)tile*64 + lane)*8) = v;
}

// ---------------- mask pack: bool bytes -> u64 bitmask per 64-key tile ------
__global__ __launch_bounds__(256) void k_maskpack(const unsigned char* __restrict__ amask,
                                                  u64* __restrict__ maskb){
  const int lane = threadIdx.x & 63;
  const int w = blockIdx.x*4 + (threadIdx.x >> 6);
  if (w >= NB_*S0_*NT_) return;
  int b = w / (S0_*NT_);
  int rem = w - b*(S0_*NT_);
  int q = rem / NT_;
  int t = rem - q*NT_;
  int key = t*64 + lane;
  unsigned char v = 0;
  if (key < S1_) v = amask[((size_t)(b*S_TOT + q))*S_TOT + S0_ + key];
  u64 bits = __ballot(v != 0);
  if (lane == 0) maskb[w] = bits;
}

// ---------------- kernel 1a: x = LN(seq@W_init + b) -> bf16 -----------------
__global__ __launch_bounds__(256) void k_x(
    const float* __restrict__ seq, const short* __restrict__ Wp,
    const float* __restrict__ b_init,
    const float* __restrict__ ln_g, const float* __restrict__ ln_b,
    short* __restrict__ xb)
{
  __shared__ short s_a[64*XPAD];
  const int tid = threadIdx.x, lane = tid & 63, wv = tid >> 6;
  const int R0 = blockIdx.x * 64;
  const int colb = lane & 15, khi = (lane>>4)<<2;

  for (int c = tid; c < 64*64; c += 256){
    int row = c >> 6, c4 = (c & 63) << 2;
    float4 f = *reinterpret_cast<const float4*>(seq + (size_t)(R0+row)*D_ + c4);
    short4v h = { f2bf(f.x), f2bf(f.y), f2bf(f.z), f2bf(f.w) };
    *reinterpret_cast<short4v*>(&s_a[row*XPAD + c4]) = h;
  }
  __syncthreads();

  f32x4 acc[16];
  #pragma unroll
  for (int nt=0;nt<16;++nt) acc[nt] = (f32x4){0.f,0.f,0.f,0.f};

  const short* arow = &s_a[(wv*16 + colb)*XPAD];
  #pragma unroll
  for (int kt=0; kt<8; ++kt){
    short8v a = load_afrag(arow, kt, khi);
    #pragma unroll
    for (int nt=0; nt<16; ++nt){
      short8v b = *reinterpret_cast<const short8v*>(Wp + ((size_t)(nt*8 + kt)*64 + lane)*8);
      acc[nt] = __builtin_amdgcn_mfma_f32_16x16x32_bf16(a, b, acc[nt], 0, 0, 0);
    }
  }

  float sum[4] = {0.f,0.f,0.f,0.f};
  #pragma unroll
  for (int nt=0; nt<16; ++nt){
    float bv = b_init[nt*16 + colb];
    #pragma unroll
    for (int r=0;r<4;++r){ acc[nt][r] += bv; sum[r] += acc[nt][r]; }
  }
  #pragma unroll
  for (int r=0;r<4;++r){
    #pragma unroll
    for (int m=1;m<16;m<<=1) sum[r] += __shfl_xor(sum[r], m, 64);
    sum[r] *= (1.f/256.f);
  }
  float var[4] = {0.f,0.f,0.f,0.f};
  #pragma unroll
  for (int nt=0; nt<16; ++nt)
    #pragma unroll
    for (int r=0;r<4;++r){ float d = acc[nt][r]-sum[r]; var[r] += d*d; }
  #pragma unroll
  for (int r=0;r<4;++r){
    #pragma unroll
    for (int m=1;m<16;m<<=1) var[r] += __shfl_xor(var[r], m, 64);
    var[r] = rsqrtf(var[r]*(1.f/256.f) + 1e-5f);
  }
  #pragma unroll
  for (int nt=0; nt<16; ++nt){
    int col = nt*16 + colb;
    float g = ln_g[col], bb = ln_b[col];
    #pragma unroll
    for (int r=0;r<4;++r){
      float xn = (acc[nt][r]-sum[r])*var[r]*g + bb;
      s_a[(wv*16 + ((lane>>4)<<2) + r)*XPAD + col] = f2bf(xn);
    }
  }
  __syncthreads();
  for (int c = tid; c < 64*32; c += 256){
    int row = c >> 5, c8 = (c & 31) << 3;
    *reinterpret_cast<short8v*>(xb + (size_t)(R0+row)*D_ + c8) =
        *reinterpret_cast<const short8v*>(&s_a[row*XPAD + c8]);
  }
}

// ---------------- kernel 1c: Z = silu(x@W_Z+b) -> bf16 row-major ------------
__global__ __launch_bounds__(256) void k_gemmZ(
    const short* __restrict__ xb, const short* __restrict__ Wp,
    const float* __restrict__ bias, short* __restrict__ Zb)
{
  __shared__ short s_a[64*XPAD];
  const int tid = threadIdx.x, lane = tid & 63, wv = tid >> 6;
  const int wy = wv >> 1, wx = wv & 1;
  const int R0 = blockIdx.x * 64;
  const int C0 = blockIdx.y * 64;
  const int colb = lane & 15, khi = (lane>>4)<<2;

  for (int c = tid; c < 64*32; c += 256){
    int r = c >> 5, c8 = (c & 31) << 3;
    size_t xrow = (size_t)(R0 + r);
    *reinterpret_cast<short8v*>(&s_a[r*XPAD + c8]) =
        *reinterpret_cast<const short8v*>(xb + xrow*D_ + c8);
  }
  __syncthreads();

  f32x4 acc[2][2];
  #pragma unroll
  for(int i=0;i<2;++i)
    #pragma unroll
    for(int j=0;j<2;++j) acc[i][j] = (f32x4){0.f,0.f,0.f,0.f};

  const short* ar0 = &s_a[(wy*32 + colb)*XPAD];
  const short* ar1 = ar0 + 16*XPAD;
  const int ntg = (C0 >> 4) + wx*2;
  #pragma unroll
  for (int kt=0; kt<8; ++kt){
    short8v a0 = load_afrag(ar0, kt, khi);
    short8v a1 = load_afrag(ar1, kt, khi);
    short8v b0 = *reinterpret_cast<const short8v*>(Wp + ((size_t)((ntg+0)*8 + kt)*64 + lane)*8);
    short8v b1 = *reinterpret_cast<const short8v*>(Wp + ((size_t)((ntg+1)*8 + kt)*64 + lane)*8);
    acc[0][0] = __builtin_amdgcn_mfma_f32_16x16x32_bf16(a0, b0, acc[0][0], 0,0,0);
    acc[0][1] = __builtin_amdgcn_mfma_f32_16x16x32_bf16(a0, b1, acc[0][1], 0,0,0);
    acc[1][0] = __builtin_amdgcn_mfma_f32_16x16x32_bf16(a1, b0, acc[1][0], 0,0,0);
    acc[1][1] = __builtin_amdgcn_mfma_f32_16x16x32_bf16(a1, b1, acc[1][1], 0,0,0);
  }
  #pragma unroll
  for (int sj=0; sj<2; ++sj){
    int col = C0 + wx*32 + sj*16 + colb;
    float bv = bias[col];
    #pragma unroll
    for (int si=0; si<2; ++si){
      #pragma unroll
      for (int r=0;r<4;++r){
        int orow = R0 + wy*32 + si*16 + ((lane>>4)<<2) + r;
        Zb[(size_t)orow*DZ_ + col] = f2bf(silu_f(acc[si][sj][r] + bv));
      }
    }
  }
}

// ------- kernel 1c2: pack Z key rows -> A-fragment order (for flash QK) -----
__global__ __launch_bounds__(256) void k_packZ(const short* __restrict__ Zb,
                                               short* __restrict__ ZkF){
  const int lane = threadIdx.x & 63;
  const int w = blockIdx.x*4 + (threadIdx.x >> 6);
  if (w >= NB_*KT16_*4) return;
  const int b = w / (KT16_*4);
  const int rem = w - b*(KT16_*4);
  const int kt16 = rem >> 2, kt = rem & 3;
  int key = kt16*16 + (lane & 15); if (key > 1024) key = 1024;
  const short* zr = Zb + ((size_t)(b*S_TOT + S0_ + key))*DZ_ + kt*32 + ((lane>>4)<<2);
  short4v lo = *reinterpret_cast<const short4v*>(zr);
  short4v hi = *reinterpret_cast<const short4v*>(zr + 16);
  short8v f = {lo[0],lo[1],lo[2],lo[3],hi[0],hi[1],hi[2],hi[3]};
  *reinterpret_cast<short8v*>(ZkF + ((size_t)w*64 + lane)*8) = f;
}

// ---------------- kernel 1d: V -> bf16 B-fragment order VtF -----------------
__global__ __launch_bounds__(256) void k_gemmV(
    const short* __restrict__ xb, const short* __restrict__ Wp,
    const float* __restrict__ bias, short* __restrict__ VtF)
{
  __shared__ short s_a[64*XPAD];
  __shared__ short s_t[64][72];
  const int tid = threadIdx.x, lane = tid & 63, wv = tid >> 6;
  const int wy = wv >> 1, wx = wv & 1;
  const int R0 = blockIdx.x * 64;     // key base within batch (tile t = R0/64)
  const int C0 = blockIdx.y * 64;     // v base
  const int b  = blockIdx.z;
  const int colb = lane & 15, khi = (lane>>4)<<2;

  for (int c = tid; c < 64*32; c += 256){
    int r = c >> 5, c8 = (c & 31) << 3;
    int k = R0 + r; if (k > 1024) k = 1024;
    size_t xrow = (size_t)b*S_TOT + S0_ + k;
    *reinterpret_cast<short8v*>(&s_a[r*XPAD + c8]) =
        *reinterpret_cast<const short8v*>(xb + xrow*D_ + c8);
  }
  __syncthreads();

  f32x4 acc[2][2];
  #pragma unroll
  for(int i=0;i<2;++i)
    #pragma unroll
    for(int j=0;j<2;++j) acc[i][j] = (f32x4){0.f,0.f,0.f,0.f};

  const short* ar0 = &s_a[(wy*32 + colb)*XPAD];
  const short* ar1 = ar0 + 16*XPAD;
  const int ntg = (C0 >> 4) + wx*2;
  #pragma unroll
  for (int kt=0; kt<8; ++kt){
    short8v a0 = load_afrag(ar0, kt, khi);
    short8v a1 = load_afrag(ar1, kt, khi);
    short8v b0 = *reinterpret_cast<const short8v*>(Wp + ((size_t)((ntg+0)*8 + kt)*64 + lane)*8);
    short8v b1 = *reinterpret_cast<const short8v*>(Wp + ((size_t)((ntg+1)*8 + kt)*64 + lane)*8);
    acc[0][0] = __builtin_amdgcn_mfma_f32_16x16x32_bf16(a0, b0, acc[0][0], 0,0,0);
    acc[0][1] = __builtin_amdgcn_mfma_f32_16x16x32_bf16(a0, b1, acc[0][1], 0,0,0);
    acc[1][0] = __builtin_amdgcn_mfma_f32_16x16x32_bf16(a1, b0, acc[1][0], 0,0,0);
    acc[1][1] = __builtin_amdgcn_mfma_f32_16x16x32_bf16(a1, b1, acc[1][1], 0,0,0);
  }
  // silu + transpose into LDS [v_local][key_local]
  #pragma unroll
  for (int sj=0; sj<2; ++sj){
    int cl = wx*32 + sj*16 + colb;
    float bv = bias[C0 + cl];
    #pragma unroll
    for (int si=0; si<2; ++si){
      #pragma unroll
      for (int r=0;r<4;++r){
        int rl = wy*32 + si*16 + ((lane>>4)<<2) + r;
        s_t[cl][rl] = f2bf(silu_f(acc[si][sj][r] + bv));
      }
    }
  }
  __syncthreads();
  // emit B-fragments (zero pad for key >= S1_)
  {
    const int vt_l = tid >> 6;           // 0..3: v-tile within C0
    const int vloc = vt_l*16 + (lane & 15);
    const int krow = (lane>>4)<<2;
    const int t = R0 >> 6;
    #pragma unroll
    for (int kt=0; kt<2; ++kt){
      short8v f;
      #pragma unroll
      for (int j=0;j<8;++j){
        int kl = kt*32 + krow + (j&3) + ((j>>2)<<4);
        short v = s_t[vloc][kl];
        if (R0 + kl >= S1_) v = 0;
        f[j] = v;
      }
      size_t o = (((size_t)b*32 + (C0>>4) + vt_l)*(2*NT_) + 2*t + kt)*64 + lane;
      *reinterpret_cast<short8v*>(VtF + o*8) = f;
    }
  }
}

// ------ kernel 2: fused flash attention + U-proj + out-proj + gating --------
// block = (batch b, q-tile of 16); wave wv owns v-slice wv*128..+127
__global__ __launch_bounds__(256,2) void k_flash(
    const short* __restrict__ Zb, const short* __restrict__ ZkF,
    const short* __restrict__ VtF, const u64* __restrict__ maskb,
    const short* __restrict__ xb,
    const short* __restrict__ WpU, const float* __restrict__ b_U,
    const short* __restrict__ Wpo, const float* __restrict__ b_out,
    const short* __restrict__ Wpg, const float* __restrict__ b_gate,
    const float* __restrict__ seq, float* __restrict__ out,
    const int* __restrict__ heights,
    const float* __restrict__ os_g, const float* __restrict__ os_b,
    const float* __restrict__ embH)
{
  __shared__ short  s_qg[16][132];
  __shared__ float  s_qh[16][12];
  __shared__ float  s_qb[16];
  __shared__ int    s_hk[NT_*64];
  __shared__ u64    s_mb[16][NT_];
  __shared__ float  s_mx[2][4][16];
  __shared__ float  s_sm[2][4][16];
  __shared__ short8v s_pl[8][64];   // [buf*4 + tile][lane]
  __shared__ short8v s_ph[8][64];
  __shared__ short  sX [16*XPAD];   // x rows for this q-tile (bf16)
  __shared__ short  sUV[16*UPAD];   // U * V_ (bf16)
  __shared__ short  sO [16*XPAD];   // o (bf16)
  __shared__ short  sR [16*XPAD];   // res (bf16)

  const int tid = threadIdx.x, lane = tid & 63, wv = tid >> 6;
  const int b  = blockIdx.x & 7;
  const int qt = blockIdx.x >> 3;
  const int q0 = qt * 16;

  // ---- stage x rows (bf16) and res rows (fp32 -> bf16)
  for (int c = tid; c < 16*32; c += 256){
    int r = c >> 5, c8 = (c & 31) << 3;
    int q = min(q0 + r, S0_-1);
    *reinterpret_cast<short8v*>(&sX[r*XPAD + c8]) =
        *reinterpret_cast<const short8v*>(xb + ((size_t)(b*S_TOT + q))*D_ + c8);
  }
  for (int c = tid; c < 16*64; c += 256){
    int r = c >> 6, c4 = (c & 63) << 2;
    int q = min(q0 + r, S0_-1);
    float4 f = *reinterpret_cast<const float4*>(seq + ((size_t)(b*S_TOT + q))*D_ + c4);
    short4v h = { f2bf(f.x), f2bf(f.y), f2bf(f.z), f2bf(f.w) };
    *reinterpret_cast<short4v*>(&sR[r*XPAD + c4]) = h;
  }

  // ---- Q prep: 16 threads per q-row, 8 dz each
  {
    int row = tid >> 4, part = tid & 15;
    int q = q0 + row; if (q > S0_-1) q = S0_-1;
    const short* zrow = Zb + ((size_t)(b*S_TOT + q))*DZ_ + part*8;
    float qb_acc = 0.f;
    float qh_acc[10];
    #pragma unroll
    for (int h=0;h<10;++h) qh_acc[h] = 0.f;
    #pragma unroll
    for (int e=0; e<8; ++e){
      int dz = part*8 + e;
      float z = bf2f(zrow[e]);
      float Q  = z*os_g[dz]      + os_b[dz];
      float Qp = z*os_g[DZ_+dz]  + os_b[DZ_+dz];
      s_qg[row][dz] = f2bf(Q * os_g[2*DZ_+dz]);
      qb_acc += Q * os_b[2*DZ_+dz];
      #pragma unroll
      for (int h=0;h<10;++h) qh_acc[h] += Qp * embH[h*DZ_ + dz];
    }
    #pragma unroll
    for (int m=1;m<16;m<<=1){
      qb_acc += __shfl_xor(qb_acc, m, 64);
      #pragma unroll
      for (int h=0;h<10;++h) qh_acc[h] += __shfl_xor(qh_acc[h], m, 64);
    }
    if (part == 0){
      s_qb[row] = qb_acc;
      #pragma unroll
      for (int h=0;h<10;++h) s_qh[row][h] = qh_acc[h];
    }
  }
  for (int k = tid; k < NT_*64; k += 256)
    s_hk[k] = (k < S1_) ? heights[b*S_TOT + S0_ + k] : 0;
  for (int idx = tid; idx < 16*NT_; idx += 256){
    int qq = idx / NT_, tt = idx - qq*NT_;
    int qr = q0 + qq; if (qr > S0_-1) qr = S0_-1;
    s_mb[qq][tt] = maskb[((size_t)(b*S0_ + qr))*NT_ + tt];
  }
  __syncthreads();

  const int qcol = lane & 15, khi = (lane>>4)<<2;
  int qme = q0 + qcol; if (qme > S0_-1) qme = S0_-1;
  const int hq = heights[b*S_TOT + qme];
  const float qb = s_qb[qcol];

  short8v qgf[4];
  #pragma unroll
  for (int kt=0; kt<4; ++kt) qgf[kt] = load_afrag(&s_qg[qcol][0], kt, khi);

  float mcol = -1e30f;
  float mrow[4] = {-1e30f,-1e30f,-1e30f,-1e30f};
  float lrow[4] = {0.f,0.f,0.f,0.f};
  f32x4 O[8];
  #pragma unroll
  for (int vt=0; vt<8; ++vt) O[vt] = (f32x4){0.f,0.f,0.f,0.f};

  int buf = 0;
  for (int it=0; it<5; ++it){
    const int t = it*4 + wv;
    const bool tvalid = (t < NT_);
    f32x4 sc[4];
    float tm = -1e30f;
    // ---- phase A: own tile's QK^T + bias + mask
    if (tvalid){
      #pragma unroll
      for (int st=0; st<4; ++st){
        f32x4 c = (f32x4){0.f,0.f,0.f,0.f};
        #pragma unroll
        for (int kt=0; kt<4; ++kt){
          short8v a = *reinterpret_cast<const short8v*>(
              ZkF + (((size_t)(b*KT16_ + t*4 + st)*4 + kt)*64 + lane)*8);
          c = __builtin_amdgcn_mfma_f32_16x16x32_bf16(a, qgf[kt], c, 0,0,0);
        }
        sc[st] = c;
      }
      u64 mb = s_mb[qcol][t];
      #pragma unroll
      for (int st=0; st<4; ++st){
        int4 hk4 = *reinterpret_cast<const int4*>(&s_hk[t*64 + st*16 + khi]);
        #pragma unroll
        for (int r=0;r<4;++r){
          int hk = (&hk4.x)[r];
          int idx = min(max(hk - hq, 1), 10) - 1;
          float v = (sc[st][r] + qb + s_qh[qcol][idx]) * SCALE_INV;
          int kl = st*16 + khi + r;
          v = ((mb >> kl) & 1ull) ? v : -9999.f;
          sc[st][r] = v;
          tm = fmaxf(tm, v);
        }
      }
      tm = fmaxf(tm, __shfl_xor(tm, 16, 64));
      tm = fmaxf(tm, __shfl_xor(tm, 32, 64));
    }
    if (lane < 16) s_mx[buf][wv][lane] = tm;
    __syncthreads();

    // ---- phase B: combined max, defer-max rescale, exp, pack P
    float cmc = fmaxf(fmaxf(s_mx[buf][0][qcol], s_mx[buf][1][qcol]),
                      fmaxf(s_mx[buf][2][qcol], s_mx[buf][3][qcol]));
    if (__any(cmc > mcol + 8.f)){
      mcol = fmaxf(mcol, cmc);
      #pragma unroll
      for (int r=0;r<4;++r){
        int qr = khi + r;
        float cmr = fmaxf(fmaxf(s_mx[buf][0][qr], s_mx[buf][1][qr]),
                          fmaxf(s_mx[buf][2][qr], s_mx[buf][3][qr]));
        float mn = fmaxf(mrow[r], cmr);
        float s = __expf(mrow[r] - mn);
        lrow[r] *= s; mrow[r] = mn;
        #pragma unroll
        for (int vt=0; vt<8; ++vt) O[vt][r] *= s;
      }
    }
    float ls = 0.f;
    if (tvalid){
      #pragma unroll
      for (int st=0; st<4; ++st)
        #pragma unroll
        for (int r=0;r<4;++r){
          float p = __expf(sc[st][r] - mcol);
          ls += p; sc[st][r] = p;
        }
    }
    ls += __shfl_xor(ls, 16, 64);
    ls += __shfl_xor(ls, 32, 64);
    if (lane < 16) s_sm[buf][wv][lane] = ls;
    if (tvalid){
      short8v pa0, pa1;
      #pragma unroll
      for (int j=0;j<8;++j){
        pa0[j] = f2bf(sc[(j>>2)][j&3]);
        pa1[j] = f2bf(sc[2 + (j>>2)][j&3]);
      }
      s_pl[buf*4 + wv][lane] = pa0;
      s_ph[buf*4 + wv][lane] = pa1;
    }
    __syncthreads();

    // ---- phase C: accumulate l; PV over the 4 tiles for own v-slice
    #pragma unroll
    for (int r=0;r<4;++r){
      int qr = khi + r;
      lrow[r] += s_sm[buf][0][qr] + s_sm[buf][1][qr] + s_sm[buf][2][qr] + s_sm[buf][3][qr];
    }
    #pragma unroll
    for (int tw=0; tw<4; ++tw){
      int tl = it*4 + tw;
      if (tl >= NT_) break;
      short8v pa0 = s_pl[buf*4 + tw][lane];
      short8v pa1 = s_ph[buf*4 + tw][lane];
      #pragma unroll
      for (int vt=0; vt<8; ++vt){
        size_t vb = ((size_t)b*32 + wv*8 + vt)*(2*NT_) + 2*tl;
        short8v b0 = *reinterpret_cast<const short8v*>(VtF + (vb*64 + lane)*8);
        short8v b1 = *reinterpret_cast<const short8v*>(VtF + ((vb+1)*64 + lane)*8);
        O[vt] = __builtin_amdgcn_mfma_f32_16x16x32_bf16(pa0, b0, O[vt], 0,0,0);
        O[vt] = __builtin_amdgcn_mfma_f32_16x16x32_bf16(pa1, b1, O[vt], 0,0,0);
      }
    }
    buf ^= 1;
  }

  // ---- U = silu(x @ W_U + b) for own v-slice; uv = U * O / l -> sUV (bf16)
  f32x4 accu[8];
  #pragma unroll
  for (int vt=0; vt<8; ++vt) accu[vt] = (f32x4){0.f,0.f,0.f,0.f};
  {
    const short* xrow = &sX[qcol*XPAD];
    #pragma unroll
    for (int kt=0; kt<8; ++kt){
      short8v a = load_afrag(xrow, kt, khi);
      #pragma unroll
      for (int vt=0; vt<8; ++vt){
        int nt = wv*8 + vt;
        short8v bw = *reinterpret_cast<const short8v*>(WpU + ((size_t)(nt*8 + kt)*64 + lane)*8);
        accu[vt] = __builtin_amdgcn_mfma_f32_16x16x32_bf16(a, bw, accu[vt], 0,0,0);
      }
    }
  }
  float inv[4];
  #pragma unroll
  for (int r=0;r<4;++r) inv[r] = 1.f / lrow[r];
  #pragma unroll
  for (int vt=0; vt<8; ++vt){
    int v = wv*128 + vt*16 + qcol;
    float bu = b_U[v];
    #pragma unroll
    for (int r=0;r<4;++r){
      float u = silu_f(accu[vt][r] + bu);
      sUV[(khi + r)*UPAD + v] = f2bf(u * O[vt][r] * inv[r]);
    }
  }
  __syncthreads();

  // ---- out-proj: o = UV @ W_out + b (each wave: 4 n-tiles, K=512)
  f32x4 acc_o[4];
  #pragma unroll
  for (int j=0;j<4;++j) acc_o[j] = (f32x4){0.f,0.f,0.f,0.f};
  {
    const short* arow = &sUV[qcol*UPAD];
    #pragma unroll
    for (int kt=0; kt<16; ++kt){
      short8v a = load_afrag(arow, kt, khi);
      #pragma unroll
      for (int j=0;j<4;++j){
        int nt = wv*4 + j;
        short8v bw = *reinterpret_cast<const short8v*>(Wpo + ((size_t)(nt*16 + kt)*64 + lane)*8);
        acc_o[j] = __builtin_amdgcn_mfma_f32_16x16x32_bf16(a, bw, acc_o[j], 0,0,0);
      }
    }
  }
  #pragma unroll
  for (int j=0;j<4;++j){
    int col = (wv*4+j)*16 + qcol;
    float bv = b_out[col];
    #pragma unroll
    for (int r=0;r<4;++r){
      acc_o[j][r] += bv;
      sO[(khi + r)*XPAD + col] = f2bf(acc_o[j][r]);
    }
  }
  __syncthreads();

  // ---- gate = sigmoid([o, res] @ W_gate + b); final mix + write
  f32x4 acc_g[4];
  #pragma unroll
  for (int j=0;j<4;++j) acc_g[j] = (f32x4){0.f,0.f,0.f,0.f};
  {
    const short* orow_p = &sO[qcol*XPAD];
    const short* rrow_p = &sR[qcol*XPAD];
    #pragma unroll
    for (int kt=0; kt<8; ++kt){
      short8v a = load_afrag(orow_p, kt, khi);
      #pragma unroll
      for (int j=0;j<4;++j){
        int nt = wv*4 + j;
        short8v bw = *reinterpret_cast<const short8v*>(Wpg + ((size_t)(nt*16 + kt)*64 + lane)*8);
        acc_g[j] = __builtin_amdgcn_mfma_f32_16x16x32_bf16(a, bw, acc_g[j], 0,0,0);
      }
    }
    #pragma unroll
    for (int kt=0; kt<8; ++kt){
      short8v a = load_afrag(rrow_p, kt, khi);
      #pragma unroll
      for (int j=0;j<4;++j){
        int nt = wv*4 + j;
        short8v bw = *reinterpret_cast<const short8v*>(Wpg + ((size_t)(nt*16 + 8 + kt)*64 + lane)*8);
        acc_g[j] = __builtin_amdgcn_mfma_f32_16x16x32_bf16(a, bw, acc_g[j], 0,0,0);
      }
    }
  }
  #pragma unroll
  for (int j=0;j<4;++j){
    int col = (wv*4+j)*16 + qcol;
    float bg = b_gate[col];
    #pragma unroll
    for (int r=0;r<4;++r){
      int q = q0 + khi + r;
      if (q < S0_){
        float res = seq[((size_t)(b*S_TOT + q))*D_ + col];
        float g = 1.f/(1.f + __expf(-(acc_g[j][r] + bg)));
        out[((size_t)(b*S_TOT + q))*D_ + col] = g*acc_o[j][r] + (1.f-g)*res;
      }
    }
  }
}

// ---------------- kernel 4: passthrough tail rows ---------------------------
__global__ void k_copy(const float* __restrict__ seq, float* __restrict__ out){
  const int per_b = S1_ * (D_/4);
  const int total = NB_ * per_b;
  for (int i = blockIdx.x*blockDim.x + threadIdx.x; i < total; i += gridDim.x*blockDim.x) {
    int b = i / per_b;
    int off = i - b*per_b;
    size_t base = ((size_t)b*S_TOT + S0_) * (size_t)(D_/4);
    reinterpret_cast<float4*>(out)[base + off] =
        reinterpret_cast<const float4*>(seq)[base + off];
  }
}

extern "C" void kernel_launch(void* const* d_in, const int* in_sizes, int n_in,
                              void* d_out, int out_size, void* d_ws, size_t ws_size,
                              hipStream_t stream)
{
  const float* seq    = (const float*)d_in[0];
  const unsigned char* amask = (const unsigned char*)d_in[1];
  const int*   heights= (const int*)d_in[2];
  const float* W_init = (const float*)d_in[3];
  const float* b_init = (const float*)d_in[4];
  const float* ln_g   = (const float*)d_in[5];
  const float* ln_b   = (const float*)d_in[6];
  const float* W_U    = (const float*)d_in[7];
  const float* b_U    = (const float*)d_in[8];
  const float* W_V    = (const float*)d_in[9];
  const float* b_V    = (const float*)d_in[10];
  const float* W_Z    = (const float*)d_in[11];
  const float* b_Z    = (const float*)d_in[12];
  const float* os_g   = (const float*)d_in[13];
  const float* os_b   = (const float*)d_in[14];
  const float* embH   = (const float*)d_in[15];
  const float* W_out  = (const float*)d_in[16];
  const float* b_out  = (const float*)d_in[17];
  const float* W_gate = (const float*)d_in[18];
  const float* b_gate = (const float*)d_in[19];
  float* out = (float*)d_out;

  char* w = (char*)d_ws;
  short* Zb  = (short*)w;                w += (size_t)16512*128*2;         // bf16 Z row-major
  short* VtF = (short*)w;                w += (size_t)8*32*(2*NT_)*64*8*2; // V B-frags
  short* ZkF = (short*)w;                w += (size_t)NB_*KT16_*4*64*8*2;  // Z-key A-frags
  short* xb  = (short*)w;                w += (size_t)16384*256*2;
  u64*  maskb = (u64*)w;                 w += (size_t)NB_*S0_*NT_*8;
  short* WpI = (short*)w;                w += (size_t)65536*2;
  short* WpU = (short*)w;                w += (size_t)131072*2;
  short* WpV = (short*)w;                w += (size_t)131072*2;
  short* WpZ = (short*)w;                w += (size_t)32768*2;
  short* WpO = (short*)w;                w += (size_t)131072*2;
  short* WpG = (short*)w;                w += (size_t)131072*2;

  hipLaunchKernelGGL(k_pack, dim3(32), dim3(256), 0, stream, W_init, WpI, 256, 256);
  hipLaunchKernelGGL(k_pack, dim3(64), dim3(256), 0, stream, W_U,   WpU, 256, 512);
  hipLaunchKernelGGL(k_pack, dim3(64), dim3(256), 0, stream, W_V,   WpV, 256, 512);
  hipLaunchKernelGGL(k_pack, dim3(16), dim3(256), 0, stream, W_Z,   WpZ, 256, 128);
  hipLaunchKernelGGL(k_pack, dim3(64), dim3(256), 0, stream, W_out, WpO, 512, 256);
  hipLaunchKernelGGL(k_pack, dim3(64), dim3(256), 0, stream, W_gate,WpG, 512, 256);
  hipLaunchKernelGGL(k_maskpack, dim3((NB_*S0_*NT_ + 3)/4), dim3(256), 0, stream, amask, maskb);

  hipLaunchKernelGGL(k_x, dim3(256), dim3(256), 0, stream,
      seq, WpI, b_init, ln_g, ln_b, xb);

  hipLaunchKernelGGL(k_gemmZ, dim3(256, 2), dim3(256), 0, stream,
      xb, WpZ, b_Z, Zb);
  hipLaunchKernelGGL(k_packZ, dim3((NB_*KT16_*4 + 3)/4), dim3(256), 0, stream, Zb, ZkF);
  hipLaunchKernelGGL(k_gemmV, dim3(17, 8, 8), dim3(256), 0, stream,
      xb, WpV, b_V, VtF);

  hipLaunchKernelGGL(k_flash, dim3(512), dim3(256), 0, stream,
      Zb, ZkF, VtF, maskb, xb, WpU, b_U, WpO, b_out, WpG, b_gate,
      seq, out, heights, os_g, os_b, embH);

  hipLaunchKernelGGL(k_copy, dim3(512), dim3(256), 0, stream, seq, out);
}